// Round 1
// baseline (4893.488 us; speedup 1.0000x reference)
//
#include <hip/hip_runtime.h>

#define NP 4096
#define BB 2

__device__ __forceinline__ float wsum(float v){
  #pragma unroll
  for (int o = 32; o; o >>= 1) v += __shfl_down(v, o, 64);
  return v;
}
__device__ __forceinline__ float wmax(float v){
  #pragma unroll
  for (int o = 32; o; o >>= 1) v = fmaxf(v, __shfl_down(v, o, 64));
  return v;
}

// ---------------------------------------------------------------------------
// conv1: [128,3] x x[B,N,3] -> h0[B,128,N], bn+relu
__global__ __launch_bounds__(256) void k_conv1(
    const float* __restrict__ x, const float* __restrict__ w,
    const float* __restrict__ g, const float* __restrict__ bb,
    float* __restrict__ out)
{
  const int n = blockIdx.x * 256 + threadIdx.x;
  const int b = blockIdx.y;
  const float x0 = x[((size_t)b * NP + n) * 3 + 0];
  const float x1 = x[((size_t)b * NP + n) * 3 + 1];
  const float x2 = x[((size_t)b * NP + n) * 3 + 2];
  for (int o = 0; o < 128; ++o) {
    float v = w[o*3]*x0 + w[o*3+1]*x1 + w[o*3+2]*x2;
    v = v * (g[o] * rsqrtf(1.f + 1e-5f)) + bb[o];
    v = fmaxf(v, 0.f);
    out[((size_t)b * 128 + o) * NP + n] = v;
  }
}

// ---------------------------------------------------------------------------
// generic 1x1-conv GEMM: out[b,o,n] = act(bn( sum_c W[o,c]*(in - in2)[b,c,n] + convb )) (+res)
// ACT: 0 none, 1 relu, 2 leaky(0.2)
template<int ACT, bool SUB, bool RES, bool BN>
__global__ __launch_bounds__(256) void k_gemm(
    const float* __restrict__ in, int in_bs,
    const float* __restrict__ in2, int in2_bs,
    const float* __restrict__ res, int res_bs,
    const float* __restrict__ W, int wstride,
    const float* __restrict__ convb, int convb_bs,
    const float* __restrict__ bng, const float* __restrict__ bnb,
    float* __restrict__ out, int out_bs,
    int O, int Cin)
{
  const int n  = blockIdx.x * 256 + threadIdx.x;
  const int o0 = blockIdx.y * 32;
  const int b  = blockIdx.z;
  __shared__ float wt[32][64];
  float acc[32];
  #pragma unroll
  for (int j = 0; j < 32; ++j) acc[j] = 0.f;
  const float* inb  = in + (size_t)b * in_bs;
  const float* in2b = SUB ? in2 + (size_t)b * in2_bs : (const float*)nullptr;

  for (int cc = 0; cc < Cin; cc += 64) {
    __syncthreads();
    for (int l = threadIdx.x; l < 32 * 64; l += 256) {
      const int j = l >> 6, c = l & 63;
      float wv = 0.f;
      if (o0 + j < O) wv = W[(size_t)(o0 + j) * wstride + cc + c];
      wt[j][c] = wv;
    }
    __syncthreads();
    #pragma unroll 4
    for (int c = 0; c < 64; ++c) {
      float rh = inb[(size_t)(cc + c) * NP + n];
      if (SUB) rh -= in2b[(size_t)(cc + c) * NP + n];
      #pragma unroll
      for (int j = 0; j < 32; ++j) acc[j] += wt[j][c] * rh;
    }
  }
  #pragma unroll
  for (int j = 0; j < 32; ++j) {
    const int o = o0 + j;
    if (o < O) {
      float v = acc[j];
      if (convb) v += convb[(size_t)convb_bs * b + o];
      if (BN) v = v * (bng[o] * rsqrtf(1.f + 1e-5f)) + bnb[o];
      if (ACT == 1) v = fmaxf(v, 0.f);
      if (ACT == 2) v = v > 0.f ? v : 0.2f * v;
      if (RES) v += res[(size_t)b * res_bs + (size_t)o * NP + n];
      out[(size_t)b * out_bs + (size_t)o * NP + n] = v;
    }
  }
}

// ---------------------------------------------------------------------------
// transpose q [B,32,N] -> qT [B,N,32]
__global__ __launch_bounds__(256) void k_qT(const float* __restrict__ q, float* __restrict__ qT)
{
  const int n = blockIdx.x * 256 + threadIdx.x;
  const int b = blockIdx.y;
  const float* qb = q + (size_t)b * 32 * NP;
  float* o = qT + ((size_t)b * NP + n) * 32;
  #pragma unroll
  for (int c = 0; c < 32; ++c) o[c] = qb[(size_t)c * NP + n];
}

// ---------------------------------------------------------------------------
// pass A: row softmax stats over m-chunks of 512.  grid (16, 8, B)
__global__ __launch_bounds__(256) void k_passA(
    const float* __restrict__ qT, float* __restrict__ pmax, float* __restrict__ psum)
{
  const int n  = blockIdx.x * 256 + threadIdx.x;
  const int ms = blockIdx.y;
  const int b  = blockIdx.z;
  const float* qTb = qT + (size_t)b * NP * 32;
  float qn[32];
  #pragma unroll
  for (int c4 = 0; c4 < 8; ++c4) {
    float4 t = *(const float4*)(qTb + (size_t)n * 32 + c4 * 4);
    qn[4*c4] = t.x; qn[4*c4+1] = t.y; qn[4*c4+2] = t.z; qn[4*c4+3] = t.w;
  }
  __shared__ float qm[128][32];
  float mx = -3e38f, sm = 0.f;
  for (int t0 = 0; t0 < 4; ++t0) {
    const int m0 = ms * 512 + t0 * 128;
    __syncthreads();
    for (int l = threadIdx.x; l < 128 * 32; l += 256)
      qm[l >> 5][l & 31] = qTb[(size_t)m0 * 32 + l];
    __syncthreads();
    for (int mm = 0; mm < 128; ++mm) {
      float e = 0.f;
      #pragma unroll
      for (int c4 = 0; c4 < 8; ++c4) {
        float4 qq = *(const float4*)&qm[mm][c4 * 4];
        e += qn[4*c4]*qq.x + qn[4*c4+1]*qq.y + qn[4*c4+2]*qq.z + qn[4*c4+3]*qq.w;
      }
      const float nm = fmaxf(mx, e);
      sm = sm * __expf(mx - nm) + __expf(e - nm);
      mx = nm;
    }
  }
  pmax[((size_t)b * 8 + ms) * NP + n] = mx;
  psum[((size_t)b * 8 + ms) * NP + n] = sm;
}

__global__ __launch_bounds__(256) void k_combineA(
    const float* __restrict__ pmax, const float* __restrict__ psum,
    float* __restrict__ rmax, float* __restrict__ rinv)
{
  const int i = blockIdx.x * 256 + threadIdx.x;   // < B*NP
  const int n = i & (NP - 1);
  const int b = i >> 12;
  float mx = -3e38f;
  #pragma unroll
  for (int s = 0; s < 8; ++s) mx = fmaxf(mx, pmax[((size_t)b*8 + s) * NP + n]);
  float sm = 0.f;
  #pragma unroll
  for (int s = 0; s < 8; ++s)
    sm += psum[((size_t)b*8 + s) * NP + n] * __expf(pmax[((size_t)b*8 + s) * NP + n] - mx);
  rmax[i] = mx;
  rinv[i] = 1.f / sm;
}

// ---------------------------------------------------------------------------
// pass B: y[c,m] = sum_n v[c,n]*p[n,m], colsum[m] = sum_n p[n,m]
// grid (16 m-tiles, CSPLIT(2)*NSPLIT(4)=8, B); thread owns column m, 64 channels
__global__ __launch_bounds__(256) void k_passB(
    const float* __restrict__ qT, const float* __restrict__ v,
    const float* __restrict__ rmax, const float* __restrict__ rinv,
    float* __restrict__ ypart, float* __restrict__ csp)
{
  const int m  = blockIdx.x * 256 + threadIdx.x;
  const int cs = blockIdx.y & 1;
  const int ns = blockIdx.y >> 1;
  const int b  = blockIdx.z;
  const float* qTb = qT + (size_t)b * NP * 32;
  const float* vb  = v + (size_t)b * 128 * NP + (size_t)cs * 64 * NP;
  float qreg[32];
  #pragma unroll
  for (int c4 = 0; c4 < 8; ++c4) {
    float4 t = *(const float4*)(qTb + (size_t)m * 32 + c4 * 4);
    qreg[4*c4] = t.x; qreg[4*c4+1] = t.y; qreg[4*c4+2] = t.z; qreg[4*c4+3] = t.w;
  }
  float y[64];
  #pragma unroll
  for (int j = 0; j < 64; ++j) y[j] = 0.f;
  float csacc = 0.f;

  __shared__ float qtl[64][32];
  __shared__ float vt[64][64];
  __shared__ float rm[64], ri[64];

  const int nbeg = ns * 1024;
  for (int n0 = nbeg; n0 < nbeg + 1024; n0 += 64) {
    __syncthreads();
    for (int l = threadIdx.x; l < 64 * 32; l += 256)
      qtl[l >> 5][l & 31] = qTb[(size_t)n0 * 32 + l];
    for (int l = threadIdx.x; l < 64 * 64; l += 256) {
      const int j = l >> 6, nn = l & 63;
      vt[j][nn] = vb[(size_t)j * NP + n0 + nn];
    }
    if (threadIdx.x < 64) {
      rm[threadIdx.x] = rmax[(size_t)b * NP + n0 + threadIdx.x];
      ri[threadIdx.x] = rinv[(size_t)b * NP + n0 + threadIdx.x];
    }
    __syncthreads();
    for (int ng = 0; ng < 16; ++ng) {
      float p[4];
      #pragma unroll
      for (int k = 0; k < 4; ++k) {
        const int nn = ng * 4 + k;
        float e = 0.f;
        #pragma unroll
        for (int c4 = 0; c4 < 8; ++c4) {
          float4 qq = *(const float4*)&qtl[nn][c4 * 4];
          e += qreg[4*c4]*qq.x + qreg[4*c4+1]*qq.y + qreg[4*c4+2]*qq.z + qreg[4*c4+3]*qq.w;
        }
        p[k] = __expf(e - rm[nn]) * ri[nn];
        csacc += p[k];
      }
      #pragma unroll
      for (int j = 0; j < 64; ++j) {
        float4 vv = *(const float4*)&vt[j][ng * 4];
        y[j] += p[0]*vv.x + p[1]*vv.y + p[2]*vv.z + p[3]*vv.w;
      }
    }
  }
  #pragma unroll
  for (int j = 0; j < 64; ++j)
    ypart[(((size_t)b * 4 + ns) * 128 + cs * 64 + j) * NP + m] = y[j];
  if (cs == 0) csp[((size_t)b * 4 + ns) * NP + m] = csacc;
}

__global__ __launch_bounds__(256) void k_combineB(
    const float* __restrict__ ypart, const float* __restrict__ csp, float* __restrict__ xr)
{
  const size_t i = (size_t)blockIdx.x * 256 + threadIdx.x;  // < B*128*NP
  const int m = (int)(i & (NP - 1));
  const size_t r = i >> 12;
  const int c = (int)(r & 127);
  const int b = (int)(r >> 7);
  float s = 1e-9f, ysum = 0.f;
  #pragma unroll
  for (int ns = 0; ns < 4; ++ns) {
    ysum += ypart[(((size_t)b*4 + ns) * 128 + c) * NP + m];
    s    += csp[((size_t)b*4 + ns) * NP + m];
  }
  xr[i] = ysum / s;
}

// ---------------------------------------------------------------------------
// per-row max / mean of fuse output. grid (1024, B)
__global__ __launch_bounds__(256) void k_maxavg(
    const float* __restrict__ h, float* __restrict__ xm, float* __restrict__ xa)
{
  const int o = blockIdx.x, b = blockIdx.y;
  const float* row = h + ((size_t)b * 1024 + o) * NP;
  float mx = -3e38f, sm = 0.f;
  for (int n = threadIdx.x; n < NP; n += 256) { const float t = row[n]; mx = fmaxf(mx, t); sm += t; }
  mx = wmax(mx); sm = wsum(sm);
  __shared__ float smx[4], ssm[4];
  const int w = threadIdx.x >> 6;
  if ((threadIdx.x & 63) == 0) { smx[w] = mx; ssm[w] = sm; }
  __syncthreads();
  if (threadIdx.x == 0) {
    xm[b * 1024 + o] = fmaxf(fmaxf(smx[0], smx[1]), fmaxf(smx[2], smx[3]));
    xa[b * 1024 + o] = (ssm[0] + ssm[1] + ssm[2] + ssm[3]) * (1.f / NP);
  }
}

// cls head: [64,16] x cls_label[b,:,0], bn + leaky. 1 block, 128 threads
__global__ void k_cls(const float* __restrict__ cl, const float* __restrict__ W,
                      const float* __restrict__ g, const float* __restrict__ bb,
                      float* __restrict__ clsf)
{
  const int t = threadIdx.x;
  const int b = t >> 6, o = t & 63;
  float a = 0.f;
  #pragma unroll
  for (int j = 0; j < 16; ++j) a += W[o * 16 + j] * cl[b * 16 + j];
  a = a * (g[o] * rsqrtf(1.f + 1e-5f)) + bb[o];
  clsf[b * 64 + o] = a > 0.f ? a : 0.2f * a;
}

// glob-part of convs1 folded to a per-(b,o) bias. grid (512, B)
__global__ __launch_bounds__(256) void k_gbias(
    const float* __restrict__ W1, const float* __restrict__ xm,
    const float* __restrict__ xa, const float* __restrict__ clsf,
    const float* __restrict__ c1b, float* __restrict__ gb)
{
  const int o = blockIdx.x, b = blockIdx.y;
  float a = 0.f;
  for (int j = threadIdx.x; j < 2112; j += 256) {
    const float gv = (j < 1024) ? xm[b * 1024 + j]
                   : (j < 2048) ? xa[b * 1024 + (j - 1024)]
                                : clsf[b * 64 + (j - 2048)];
    a += W1[(size_t)o * 3136 + 1024 + j] * gv;
  }
  a = wsum(a);
  __shared__ float red[4];
  const int w = threadIdx.x >> 6;
  if ((threadIdx.x & 63) == 0) red[w] = a;
  __syncthreads();
  if (threadIdx.x == 0) gb[b * 512 + o] = red[0] + red[1] + red[2] + red[3] + c1b[o];
}

// ---------------------------------------------------------------------------
extern "C" void kernel_launch(void* const* d_in, const int* in_sizes, int n_in,
                              void* d_out, int out_size, void* d_ws, size_t ws_size,
                              hipStream_t stream)
{
  const float* x        = (const float*)d_in[0];
  const float* cls_lab  = (const float*)d_in[1];
  const float* conv1_w  = (const float*)d_in[2];
  const float* bn1_g    = (const float*)d_in[3];
  const float* bn1_b    = (const float*)d_in[4];
  const float* conv2_w  = (const float*)d_in[5];
  const float* bn2_g    = (const float*)d_in[6];
  const float* bn2_b    = (const float*)d_in[7];
  const float* sa_qk_w  = (const float*)d_in[8];
  const float* sa_v_w   = (const float*)d_in[9];
  const float* sa_v_b   = (const float*)d_in[10];
  const float* sa_t_w   = (const float*)d_in[11];
  const float* sa_t_b   = (const float*)d_in[12];
  const float* sa_bn_g  = (const float*)d_in[13];
  const float* sa_bn_b  = (const float*)d_in[14];
  const float* fuse_w   = (const float*)d_in[15];
  const float* fuse_g   = (const float*)d_in[16];
  const float* fuse_b   = (const float*)d_in[17];
  const float* label_w  = (const float*)d_in[18];
  const float* label_g  = (const float*)d_in[19];
  const float* label_b  = (const float*)d_in[20];
  const float* c1_w     = (const float*)d_in[21];
  const float* c1_b     = (const float*)d_in[22];
  const float* bns1_g   = (const float*)d_in[23];
  const float* bns1_b   = (const float*)d_in[24];
  const float* c2_w     = (const float*)d_in[25];
  const float* c2_b     = (const float*)d_in[26];
  const float* bns2_g   = (const float*)d_in[27];
  const float* bns2_b   = (const float*)d_in[28];
  const float* c3_w     = (const float*)d_in[29];
  const float* c3_b     = (const float*)d_in[30];
  float* outp = (float*)d_out;

  float* f = (float*)d_ws;
  size_t off = 0;
  float* h0    = f + off; off += (size_t)BB*128*NP;   // 1,048,576
  float* h1    = f + off; off += (size_t)BB*128*NP;
  float* hcat  = f + off; off += (size_t)BB*512*NP;   // 4,194,304
  float* q     = f + off; off += (size_t)BB*32*NP;
  float* qT    = f + off; off += (size_t)BB*32*NP;
  float* v     = f + off; off += (size_t)BB*128*NP;
  float* xr    = f + off; off += (size_t)BB*128*NP;
  float* pmax  = f + off; off += (size_t)BB*8*NP;
  float* psum  = f + off; off += (size_t)BB*8*NP;
  float* rmaxb = f + off; off += (size_t)BB*NP;
  float* rinvb = f + off; off += (size_t)BB*NP;
  float* csp   = f + off; off += (size_t)BB*4*NP;
  float* xm    = f + off; off += (size_t)BB*1024;
  float* xa    = f + off; off += (size_t)BB*1024;
  float* clsf  = f + off; off += (size_t)BB*64;
  float* gb    = f + off; off += (size_t)BB*512;
  off = (off + 255) & ~(size_t)255;
  float* ypart = f + off;                              // 16,777,216 floats
  float* fuse_out = ypart;                             // aliased (disjoint in time)
  float* out1  = fuse_out + (size_t)BB*1024*NP;
  float* out2  = out1 + (size_t)BB*512*NP;

  const dim3 blk(256);

  k_conv1<<<dim3(16, BB), blk, 0, stream>>>(x, conv1_w, bn1_g, bn1_b, h0);

  // conv2 + bn + relu
  k_gemm<1,false,false,true><<<dim3(16,4,BB), blk, 0, stream>>>(
      h0, 128*NP, nullptr,0, nullptr,0, conv2_w,128, nullptr,0, bn2_g,bn2_b,
      h1, 128*NP, 128, 128);

  for (int i = 0; i < 4; ++i) {
    const float* hin = (i == 0) ? h1 : hcat + (size_t)(i-1)*128*NP;
    const int hin_bs = (i == 0) ? 128*NP : 512*NP;

    // q = qk_w @ h
    k_gemm<0,false,false,false><<<dim3(16,1,BB), blk, 0, stream>>>(
        hin, hin_bs, nullptr,0, nullptr,0, sa_qk_w + (size_t)i*32*128,128,
        nullptr,0, nullptr,nullptr, q, 32*NP, 32, 128);
    k_qT<<<dim3(16, BB), blk, 0, stream>>>(q, qT);

    // v = v_w @ h + v_b
    k_gemm<0,false,false,false><<<dim3(16,4,BB), blk, 0, stream>>>(
        hin, hin_bs, nullptr,0, nullptr,0, sa_v_w + (size_t)i*128*128,128,
        sa_v_b + (size_t)i*128,0, nullptr,nullptr, v, 128*NP, 128, 128);

    k_passA<<<dim3(16,8,BB), blk, 0, stream>>>(qT, pmax, psum);
    k_combineA<<<dim3(BB*NP/256), blk, 0, stream>>>(pmax, psum, rmaxb, rinvb);
    k_passB<<<dim3(16,8,BB), blk, 0, stream>>>(qT, v, rmaxb, rinvb, ypart, csp);
    k_combineB<<<dim3(BB*128*NP/256), blk, 0, stream>>>(ypart, csp, xr);

    // h_new = h + relu(bn(t_w @ (h - x_r) + t_b))
    k_gemm<1,true,true,true><<<dim3(16,4,BB), blk, 0, stream>>>(
        hin, hin_bs, xr, 128*NP, hin, hin_bs, sa_t_w + (size_t)i*128*128,128,
        sa_t_b + (size_t)i*128,0, sa_bn_g + (size_t)i*128, sa_bn_b + (size_t)i*128,
        hcat + (size_t)i*128*NP, 512*NP, 128, 128);
  }

  // fuse: [1024,512] + bn + leaky(0.2)
  k_gemm<2,false,false,true><<<dim3(16,32,BB), blk, 0, stream>>>(
      hcat, 512*NP, nullptr,0, nullptr,0, fuse_w,512, nullptr,0, fuse_g,fuse_b,
      fuse_out, 1024*NP, 1024, 512);

  k_maxavg<<<dim3(1024, BB), blk, 0, stream>>>(fuse_out, xm, xa);
  k_cls<<<dim3(1), dim3(128), 0, stream>>>(cls_lab, label_w, label_g, label_b, clsf);
  k_gbias<<<dim3(512, BB), blk, 0, stream>>>(c1_w, xm, xa, clsf, c1_b, gb);

  // convs1: Cin=1024 slice of [512,3136] weight + folded glob bias, bn + relu
  k_gemm<1,false,false,true><<<dim3(16,16,BB), blk, 0, stream>>>(
      fuse_out, 1024*NP, nullptr,0, nullptr,0, c1_w,3136, gb,512, bns1_g,bns1_b,
      out1, 512*NP, 512, 1024);

  // convs2 + bias + bn + relu
  k_gemm<1,false,false,true><<<dim3(16,8,BB), blk, 0, stream>>>(
      out1, 512*NP, nullptr,0, nullptr,0, c2_w,512, c2_b,0, bns2_g,bns2_b,
      out2, 256*NP, 256, 512);

  // convs3 + bias
  k_gemm<0,false,false,false><<<dim3(16,2,BB), blk, 0, stream>>>(
      out2, 256*NP, nullptr,0, nullptr,0, c3_w,256, c3_b,0, nullptr,nullptr,
      outp, 50*NP, 50, 256);
}

// Round 3
// 1644.648 us; speedup vs baseline: 2.9754x; 2.9754x over previous
//
#include <hip/hip_runtime.h>

#define NP 4096
#define BB 2

typedef __attribute__((ext_vector_type(8))) short short8;
typedef __attribute__((ext_vector_type(4))) float f32x4;
#define MFMA_BF16 __builtin_amdgcn_mfma_f32_16x16x32_bf16

__device__ __forceinline__ float wsum(float v){
  #pragma unroll
  for (int o = 32; o; o >>= 1) v += __shfl_down(v, o, 64);
  return v;
}
__device__ __forceinline__ float wmax(float v){
  #pragma unroll
  for (int o = 32; o; o >>= 1) v = fmaxf(v, __shfl_down(v, o, 64));
  return v;
}
__device__ __forceinline__ unsigned short f2bf(float x){
  unsigned int u = __float_as_uint(x);
  return (unsigned short)((u + 0x7fffu + ((u >> 16) & 1u)) >> 16);
}
__device__ __forceinline__ short8 ld8(const unsigned short* p){
  return *(const short8*)p;
}

// ---------------------------------------------------------------------------
// conv1: [128,3] x x[B,N,3] -> h0[B,128,N], bn+relu
__global__ __launch_bounds__(256) void k_conv1(
    const float* __restrict__ x, const float* __restrict__ w,
    const float* __restrict__ g, const float* __restrict__ bb,
    float* __restrict__ out)
{
  const int n = blockIdx.x * 256 + threadIdx.x;
  const int b = blockIdx.y;
  const float x0 = x[((size_t)b * NP + n) * 3 + 0];
  const float x1 = x[((size_t)b * NP + n) * 3 + 1];
  const float x2 = x[((size_t)b * NP + n) * 3 + 2];
  for (int o = 0; o < 128; ++o) {
    float v = w[o*3]*x0 + w[o*3+1]*x1 + w[o*3+2]*x2;
    v = v * (g[o] * rsqrtf(1.f + 1e-5f)) + bb[o];
    v = fmaxf(v, 0.f);
    out[((size_t)b * 128 + o) * NP + n] = v;
  }
}

// ---------------------------------------------------------------------------
// generic 1x1-conv GEMM (fp32 VALU). OBF: write bf16 bits instead of fp32.
template<int ACT, bool SUB, bool RES, bool BN, bool OBF>
__global__ __launch_bounds__(256) void k_gemm(
    const float* __restrict__ in, int in_bs,
    const float* __restrict__ in2, int in2_bs,
    const float* __restrict__ res, int res_bs,
    const float* __restrict__ W, int wstride,
    const float* __restrict__ convb, int convb_bs,
    const float* __restrict__ bng, const float* __restrict__ bnb,
    float* __restrict__ out, int out_bs,
    int O, int Cin)
{
  const int n  = blockIdx.x * 256 + threadIdx.x;
  const int o0 = blockIdx.y * 32;
  const int b  = blockIdx.z;
  __shared__ float wt[32][64];
  float acc[32];
  #pragma unroll
  for (int j = 0; j < 32; ++j) acc[j] = 0.f;
  const float* inb  = in + (size_t)b * in_bs;
  const float* in2b = SUB ? in2 + (size_t)b * in2_bs : (const float*)nullptr;

  for (int cc = 0; cc < Cin; cc += 64) {
    __syncthreads();
    for (int l = threadIdx.x; l < 32 * 64; l += 256) {
      const int j = l >> 6, c = l & 63;
      float wv = 0.f;
      if (o0 + j < O) wv = W[(size_t)(o0 + j) * wstride + cc + c];
      wt[j][c] = wv;
    }
    __syncthreads();
    #pragma unroll 4
    for (int c = 0; c < 64; ++c) {
      float rh = inb[(size_t)(cc + c) * NP + n];
      if (SUB) rh -= in2b[(size_t)(cc + c) * NP + n];
      #pragma unroll
      for (int j = 0; j < 32; ++j) acc[j] += wt[j][c] * rh;
    }
  }
  #pragma unroll
  for (int j = 0; j < 32; ++j) {
    const int o = o0 + j;
    if (o < O) {
      float v = acc[j];
      if (convb) v += convb[(size_t)convb_bs * b + o];
      if (BN) v = v * (bng[o] * rsqrtf(1.f + 1e-5f)) + bnb[o];
      if (ACT == 1) v = fmaxf(v, 0.f);
      if (ACT == 2) v = v > 0.f ? v : 0.2f * v;
      if (RES) v += res[(size_t)b * res_bs + (size_t)o * NP + n];
      const size_t idx = (size_t)b * out_bs + (size_t)o * NP + n;
      if (OBF) ((unsigned short*)out)[idx] = f2bf(v);
      else     out[idx] = v;
    }
  }
}

// ---------------------------------------------------------------------------
// q [B,32,N] fp32 -> qT hi/lo bf16 [B,N,32]
__global__ __launch_bounds__(256) void k_qTb(
    const float* __restrict__ q, unsigned short* __restrict__ qh,
    unsigned short* __restrict__ ql)
{
  const int n = blockIdx.x * 256 + threadIdx.x;
  const int b = blockIdx.y;
  const float* qb = q + (size_t)b * 32 * NP;
  unsigned short* oh = qh + ((size_t)b * NP + n) * 32;
  unsigned short* ol = ql + ((size_t)b * NP + n) * 32;
  #pragma unroll
  for (int c = 0; c < 32; ++c) {
    const float x = qb[(size_t)c * NP + n];
    const unsigned short h = f2bf(x);
    const float hf = __uint_as_float((unsigned int)h << 16);
    oh[c] = h;
    ol[c] = f2bf(x - hf);
  }
}

// ---------------------------------------------------------------------------
// pass A (MFMA): column stats of symmetric E = Q^T Q.
// grid (64 m-tiles, 8 n-splits, B), 256 thr. Each wave w handles n-frag fi=w.
__global__ __launch_bounds__(256) void k_passA(
    const unsigned short* __restrict__ qh, const unsigned short* __restrict__ ql,
    float* __restrict__ pmax, float* __restrict__ psum)
{
  const int m0 = blockIdx.x * 64;
  const int ns = blockIdx.y;
  const int b  = blockIdx.z;
  const int tid = threadIdx.x;
  const int w = tid >> 6, lane = tid & 63, lo = lane & 15, hi = lane >> 4;
  const unsigned short* qhb = qh + (size_t)b * NP * 32;
  const unsigned short* qlb = ql + (size_t)b * NP * 32;

  short8 bh[4], bl[4];
  #pragma unroll
  for (int fj = 0; fj < 4; ++fj) {
    const int m = m0 + fj * 16 + lo;
    bh[fj] = ld8(qhb + (size_t)m * 32 + hi * 8);
    bl[fj] = ld8(qlb + (size_t)m * 32 + hi * 8);
  }
  float mx[4], sm[4];
  #pragma unroll
  for (int fj = 0; fj < 4; ++fj) { mx[fj] = -3e38f; sm[fj] = 0.f; }

  const int nbeg = ns * 512;
  for (int ch = 0; ch < 8; ++ch) {
    const int n0 = nbeg + ch * 64;
    const int nr = n0 + w * 16 + lo;
    const short8 ah = ld8(qhb + (size_t)nr * 32 + hi * 8);
    const short8 al = ld8(qlb + (size_t)nr * 32 + hi * 8);
    #pragma unroll
    for (int fj = 0; fj < 4; ++fj) {
      f32x4 e = MFMA_BF16(ah, bh[fj], (f32x4){0.f,0.f,0.f,0.f}, 0, 0, 0);
      e = MFMA_BF16(ah, bl[fj], e, 0, 0, 0);
      e = MFMA_BF16(al, bh[fj], e, 0, 0, 0);
      const float lm = fmaxf(fmaxf(e[0], e[1]), fmaxf(e[2], e[3]));
      const float nm = fmaxf(mx[fj], lm);
      sm[fj] = sm[fj] * __expf(mx[fj] - nm)
             + __expf(e[0]-nm) + __expf(e[1]-nm) + __expf(e[2]-nm) + __expf(e[3]-nm);
      mx[fj] = nm;
    }
  }
  // reduce across hi groups
  #pragma unroll
  for (int fj = 0; fj < 4; ++fj) {
    #pragma unroll
    for (int off = 16; off <= 32; off <<= 1) {
      const float om = __shfl_down(mx[fj], off, 64);
      const float os = __shfl_down(sm[fj], off, 64);
      const float nm = fmaxf(mx[fj], om);
      sm[fj] = sm[fj] * __expf(mx[fj] - nm) + os * __expf(om - nm);
      mx[fj] = nm;
    }
  }
  __shared__ float wmx[4][64], wsm[4][64];
  if (hi == 0) {
    #pragma unroll
    for (int fj = 0; fj < 4; ++fj) {
      wmx[w][fj * 16 + lo] = mx[fj];
      wsm[w][fj * 16 + lo] = sm[fj];
    }
  }
  __syncthreads();
  if (tid < 64) {
    float fm = wmx[0][tid], fs = wsm[0][tid];
    #pragma unroll
    for (int w2 = 1; w2 < 4; ++w2) {
      const float om = wmx[w2][tid], os = wsm[w2][tid];
      const float nm = fmaxf(fm, om);
      fs = fs * __expf(fm - nm) + os * __expf(om - nm);
      fm = nm;
    }
    pmax[((size_t)b * 8 + ns) * NP + m0 + tid] = fm;
    psum[((size_t)b * 8 + ns) * NP + m0 + tid] = fs;
  }
}

__global__ __launch_bounds__(256) void k_combineA(
    const float* __restrict__ pmax, const float* __restrict__ psum,
    float* __restrict__ rmax, float* __restrict__ rinv)
{
  const int i = blockIdx.x * 256 + threadIdx.x;   // < B*NP
  const int n = i & (NP - 1);
  const int b = i >> 12;
  float mx = -3e38f;
  #pragma unroll
  for (int s = 0; s < 8; ++s) mx = fmaxf(mx, pmax[((size_t)b*8 + s) * NP + n]);
  float sm = 0.f;
  #pragma unroll
  for (int s = 0; s < 8; ++s)
    sm += psum[((size_t)b*8 + s) * NP + n] * __expf(pmax[((size_t)b*8 + s) * NP + n] - mx);
  rmax[i] = mx;
  rinv[i] = 1.f / sm;
}

// ---------------------------------------------------------------------------
// pass B (MFMA): Y[128,m] += V * P over n-range, colsum[m] += 1^T P.
// grid (64 m-tiles, 4 n-splits, B), 256 thr (4 waves).
// Double-buffered P^T in LDS: one barrier per chunk; reads of buf p at chunk
// ch and writes of buf p at ch+2 are separated by the barrier at ch+1.
__global__ __launch_bounds__(256) void k_passB(
    const unsigned short* __restrict__ qh, const unsigned short* __restrict__ ql,
    const unsigned short* __restrict__ vbf,
    const float* __restrict__ rmax, const float* __restrict__ rinv,
    float* __restrict__ ypart, float* __restrict__ csp)
{
  const int m0 = blockIdx.x * 64;
  const int ns = blockIdx.y;
  const int b  = blockIdx.z;
  const int tid = threadIdx.x;
  const int w = tid >> 6, lane = tid & 63, lo = lane & 15, hi = lane >> 4;
  const unsigned short* qhb = qh + (size_t)b * NP * 32;
  const unsigned short* qlb = ql + (size_t)b * NP * 32;
  const unsigned short* vbb = vbf + (size_t)b * 128 * NP;

  __shared__ __align__(16) unsigned short Pt[2][64 * 64];  // P^T [m][n], swizzled
  __shared__ float csred[4][64];

  short8 bh[4], bl[4];
  #pragma unroll
  for (int fj = 0; fj < 4; ++fj) {
    const int m = m0 + fj * 16 + lo;
    bh[fj] = ld8(qhb + (size_t)m * 32 + hi * 8);
    bl[fj] = ld8(qlb + (size_t)m * 32 + hi * 8);
  }
  f32x4 yacc[2][4];
  #pragma unroll
  for (int cf = 0; cf < 2; ++cf)
    #pragma unroll
    for (int fj = 0; fj < 4; ++fj) yacc[cf][fj] = (f32x4){0.f,0.f,0.f,0.f};
  float cs[4] = {0.f, 0.f, 0.f, 0.f};

  const int swz = (lo & 7) << 3;   // ushort-granular XOR swizzle per row
  const int c0 = w * 32;
  const int nbeg = ns * 1024;
  for (int ch = 0; ch < 16; ++ch) {
    unsigned short* Ptc = &Pt[ch & 1][0];
    const int n0 = nbeg + ch * 64;
    // ---- E tile: wave w computes rows n0+w*16..+15 for all 4 m-frags
    const int nr = n0 + w * 16 + lo;
    const short8 ah = ld8(qhb + (size_t)nr * 32 + hi * 8);
    const short8 al = ld8(qlb + (size_t)nr * 32 + hi * 8);
    f32x4 e[4];
    #pragma unroll
    for (int fj = 0; fj < 4; ++fj) {
      e[fj] = MFMA_BF16(ah, bh[fj], (f32x4){0.f,0.f,0.f,0.f}, 0, 0, 0);
      e[fj] = MFMA_BF16(ah, bl[fj], e[fj], 0, 0, 0);
      e[fj] = MFMA_BF16(al, bh[fj], e[fj], 0, 0, 0);
    }
    float rmv[4], riv[4];
    #pragma unroll
    for (int r = 0; r < 4; ++r) {
      const int n = n0 + w * 16 + hi * 4 + r;
      rmv[r] = rmax[(size_t)b * NP + n];
      riv[r] = rinv[(size_t)b * NP + n];
    }
    // ---- P tile -> LDS (write buf ch&1; no prior-read hazard thanks to dbuf)
    #pragma unroll
    for (int fj = 0; fj < 4; ++fj) {
      float p[4];
      #pragma unroll
      for (int r = 0; r < 4; ++r) p[r] = __expf(e[fj][r] - rmv[r]) * riv[r];
      cs[fj] += p[0] + p[1] + p[2] + p[3];
      ushort4 pk;
      pk.x = f2bf(p[0]); pk.y = f2bf(p[1]); pk.z = f2bf(p[2]); pk.w = f2bf(p[3]);
      const int row = fj * 16 + lo;
      const int col = (w * 16 + hi * 4) ^ swz;
      *(ushort4*)&Ptc[row * 64 + col] = pk;
    }
    // ---- V fragments (global, independent of Pt) issued before the barrier
    short8 vfrag[2][2];
    #pragma unroll
    for (int cf = 0; cf < 2; ++cf)
      #pragma unroll
      for (int ks = 0; ks < 2; ++ks)
        vfrag[cf][ks] = ld8(vbb + (size_t)(c0 + cf*16 + lo) * NP + n0 + ks*32 + hi*8);
    __syncthreads();   // Pt[ch&1] ready; also fences prior reads of this buf
    // ---- PV: wave w handles channels c0..c0+31
    #pragma unroll
    for (int ks = 0; ks < 2; ++ks) {
      #pragma unroll
      for (int fj = 0; fj < 4; ++fj) {
        const int row = fj * 16 + lo;
        const int col = (ks * 32 + hi * 8) ^ swz;
        const short8 pf = ld8(&Ptc[row * 64 + col]);
        #pragma unroll
        for (int cf = 0; cf < 2; ++cf)
          yacc[cf][fj] = MFMA_BF16(vfrag[cf][ks], pf, yacc[cf][fj], 0, 0, 0);
      }
    }
  }
  // ---- write Y partials
  float* yp = ypart + ((size_t)b * 4 + ns) * 128 * NP;
  #pragma unroll
  for (int cf = 0; cf < 2; ++cf)
    #pragma unroll
    for (int fj = 0; fj < 4; ++fj)
      #pragma unroll
      for (int r = 0; r < 4; ++r) {
        const int c = w * 32 + cf * 16 + hi * 4 + r;
        const int m = m0 + fj * 16 + lo;
        yp[(size_t)c * NP + m] = yacc[cf][fj][r];
      }
  // ---- colsum reduce
  #pragma unroll
  for (int fj = 0; fj < 4; ++fj) {
    cs[fj] += __shfl_down(cs[fj], 16, 64);
    cs[fj] += __shfl_down(cs[fj], 32, 64);
  }
  __syncthreads();   // all loop-phase LDS traffic drained before csred reuse
  if (hi == 0) {
    #pragma unroll
    for (int fj = 0; fj < 4; ++fj) csred[w][fj * 16 + lo] = cs[fj];
  }
  __syncthreads();
  if (tid < 64)
    csp[((size_t)b * 4 + ns) * NP + m0 + tid] =
        csred[0][tid] + csred[1][tid] + csred[2][tid] + csred[3][tid];
}

__global__ __launch_bounds__(256) void k_combineB(
    const float* __restrict__ ypart, const float* __restrict__ csp, float* __restrict__ xr)
{
  const size_t i = (size_t)blockIdx.x * 256 + threadIdx.x;  // < B*128*NP
  const int m = (int)(i & (NP - 1));
  const size_t r = i >> 12;
  const int c = (int)(r & 127);
  const int b = (int)(r >> 7);
  float s = 1e-9f, ysum = 0.f;
  #pragma unroll
  for (int ns = 0; ns < 4; ++ns) {
    ysum += ypart[(((size_t)b*4 + ns) * 128 + c) * NP + m];
    s    += csp[((size_t)b*4 + ns) * NP + m];
  }
  xr[i] = ysum / s;
}

// ---------------------------------------------------------------------------
__global__ __launch_bounds__(256) void k_maxavg(
    const float* __restrict__ h, float* __restrict__ xm, float* __restrict__ xa)
{
  const int o = blockIdx.x, b = blockIdx.y;
  const float* row = h + ((size_t)b * 1024 + o) * NP;
  float mx = -3e38f, sm = 0.f;
  for (int n = threadIdx.x; n < NP; n += 256) { const float t = row[n]; mx = fmaxf(mx, t); sm += t; }
  mx = wmax(mx); sm = wsum(sm);
  __shared__ float smx[4], ssm[4];
  const int w = threadIdx.x >> 6;
  if ((threadIdx.x & 63) == 0) { smx[w] = mx; ssm[w] = sm; }
  __syncthreads();
  if (threadIdx.x == 0) {
    xm[b * 1024 + o] = fmaxf(fmaxf(smx[0], smx[1]), fmaxf(smx[2], smx[3]));
    xa[b * 1024 + o] = (ssm[0] + ssm[1] + ssm[2] + ssm[3]) * (1.f / NP);
  }
}

__global__ void k_cls(const float* __restrict__ cl, const float* __restrict__ W,
                      const float* __restrict__ g, const float* __restrict__ bb,
                      float* __restrict__ clsf)
{
  const int t = threadIdx.x;
  const int b = t >> 6, o = t & 63;
  float a = 0.f;
  #pragma unroll
  for (int j = 0; j < 16; ++j) a += W[o * 16 + j] * cl[b * 16 + j];
  a = a * (g[o] * rsqrtf(1.f + 1e-5f)) + bb[o];
  clsf[b * 64 + o] = a > 0.f ? a : 0.2f * a;
}

__global__ __launch_bounds__(256) void k_gbias(
    const float* __restrict__ W1, const float* __restrict__ xm,
    const float* __restrict__ xa, const float* __restrict__ clsf,
    const float* __restrict__ c1b, float* __restrict__ gb)
{
  const int o = blockIdx.x, b = blockIdx.y;
  float a = 0.f;
  for (int j = threadIdx.x; j < 2112; j += 256) {
    const float gv = (j < 1024) ? xm[b * 1024 + j]
                   : (j < 2048) ? xa[b * 1024 + (j - 1024)]
                                : clsf[b * 64 + (j - 2048)];
    a += W1[(size_t)o * 3136 + 1024 + j] * gv;
  }
  a = wsum(a);
  __shared__ float red[4];
  const int w = threadIdx.x >> 6;
  if ((threadIdx.x & 63) == 0) red[w] = a;
  __syncthreads();
  if (threadIdx.x == 0) gb[b * 512 + o] = red[0] + red[1] + red[2] + red[3] + c1b[o];
}

// ---------------------------------------------------------------------------
extern "C" void kernel_launch(void* const* d_in, const int* in_sizes, int n_in,
                              void* d_out, int out_size, void* d_ws, size_t ws_size,
                              hipStream_t stream)
{
  const float* x        = (const float*)d_in[0];
  const float* cls_lab  = (const float*)d_in[1];
  const float* conv1_w  = (const float*)d_in[2];
  const float* bn1_g    = (const float*)d_in[3];
  const float* bn1_b    = (const float*)d_in[4];
  const float* conv2_w  = (const float*)d_in[5];
  const float* bn2_g    = (const float*)d_in[6];
  const float* bn2_b    = (const float*)d_in[7];
  const float* sa_qk_w  = (const float*)d_in[8];
  const float* sa_v_w   = (const float*)d_in[9];
  const float* sa_v_b   = (const float*)d_in[10];
  const float* sa_t_w   = (const float*)d_in[11];
  const float* sa_t_b   = (const float*)d_in[12];
  const float* sa_bn_g  = (const float*)d_in[13];
  const float* sa_bn_b  = (const float*)d_in[14];
  const float* fuse_w   = (const float*)d_in[15];
  const float* fuse_g   = (const float*)d_in[16];
  const float* fuse_b   = (const float*)d_in[17];
  const float* label_w  = (const float*)d_in[18];
  const float* label_g  = (const float*)d_in[19];
  const float* label_b  = (const float*)d_in[20];
  const float* c1_w     = (const float*)d_in[21];
  const float* c1_b     = (const float*)d_in[22];
  const float* bns1_g   = (const float*)d_in[23];
  const float* bns1_b   = (const float*)d_in[24];
  const float* c2_w     = (const float*)d_in[25];
  const float* c2_b     = (const float*)d_in[26];
  const float* bns2_g   = (const float*)d_in[27];
  const float* bns2_b   = (const float*)d_in[28];
  const float* c3_w     = (const float*)d_in[29];
  const float* c3_b     = (const float*)d_in[30];
  float* outp = (float*)d_out;

  float* f = (float*)d_ws;
  size_t off = 0;
  float* h0    = f + off; off += (size_t)BB*128*NP;
  float* h1    = f + off; off += (size_t)BB*128*NP;
  float* hcat  = f + off; off += (size_t)BB*512*NP;
  float* q     = f + off; off += (size_t)BB*32*NP;
  unsigned short* qTh = (unsigned short*)(f + off); off += (size_t)BB*NP*32/2;
  unsigned short* qTl = (unsigned short*)(f + off); off += (size_t)BB*NP*32/2;
  unsigned short* vb  = (unsigned short*)(f + off); off += (size_t)BB*128*NP/2;
  float* xr    = f + off; off += (size_t)BB*128*NP;
  float* pmax  = f + off; off += (size_t)BB*8*NP;
  float* psum  = f + off; off += (size_t)BB*8*NP;
  float* rmaxb = f + off; off += (size_t)BB*NP;
  float* rinvb = f + off; off += (size_t)BB*NP;
  float* csp   = f + off; off += (size_t)BB*4*NP;
  float* xm    = f + off; off += (size_t)BB*1024;
  float* xa    = f + off; off += (size_t)BB*1024;
  float* clsf  = f + off; off += (size_t)BB*64;
  float* gb    = f + off; off += (size_t)BB*512;
  off = (off + 255) & ~(size_t)255;
  float* ypart = f + off;                              // B*4*128*NP floats
  float* fuse_out = ypart;                             // aliased (disjoint in time)
  float* out1  = fuse_out + (size_t)BB*1024*NP;
  float* out2  = out1 + (size_t)BB*512*NP;

  const dim3 blk(256);

  k_conv1<<<dim3(16, BB), blk, 0, stream>>>(x, conv1_w, bn1_g, bn1_b, h0);

  k_gemm<1,false,false,true,false><<<dim3(16,4,BB), blk, 0, stream>>>(
      h0, 128*NP, nullptr,0, nullptr,0, conv2_w,128, nullptr,0, bn2_g,bn2_b,
      h1, 128*NP, 128, 128);

  for (int i = 0; i < 4; ++i) {
    const float* hin = (i == 0) ? h1 : hcat + (size_t)(i-1)*128*NP;
    const int hin_bs = (i == 0) ? 128*NP : 512*NP;

    // q = qk_w @ h (fp32), then split-transpose to bf16 hi/lo
    k_gemm<0,false,false,false,false><<<dim3(16,1,BB), blk, 0, stream>>>(
        hin, hin_bs, nullptr,0, nullptr,0, sa_qk_w + (size_t)i*32*128,128,
        nullptr,0, nullptr,nullptr, q, 32*NP, 32, 128);
    k_qTb<<<dim3(16, BB), blk, 0, stream>>>(q, qTh, qTl);

    // v = v_w @ h + v_b -> bf16 [128][N]
    k_gemm<0,false,false,false,true><<<dim3(16,4,BB), blk, 0, stream>>>(
        hin, hin_bs, nullptr,0, nullptr,0, sa_v_w + (size_t)i*128*128,128,
        sa_v_b + (size_t)i*128,0, nullptr,nullptr, (float*)vb, 128*NP, 128, 128);

    k_passA<<<dim3(64,8,BB), blk, 0, stream>>>(qTh, qTl, pmax, psum);
    k_combineA<<<dim3(BB*NP/256), blk, 0, stream>>>(pmax, psum, rmaxb, rinvb);
    k_passB<<<dim3(64,4,BB), blk, 0, stream>>>(qTh, qTl, vb, rmaxb, rinvb, ypart, csp);
    k_combineB<<<dim3(BB*128*NP/256), blk, 0, stream>>>(ypart, csp, xr);

    k_gemm<1,true,true,true,false><<<dim3(16,4,BB), blk, 0, stream>>>(
        hin, hin_bs, xr, 128*NP, hin, hin_bs, sa_t_w + (size_t)i*128*128,128,
        sa_t_b + (size_t)i*128,0, sa_bn_g + (size_t)i*128, sa_bn_b + (size_t)i*128,
        hcat + (size_t)i*128*NP, 512*NP, 128, 128);
  }

  k_gemm<2,false,false,true,false><<<dim3(16,32,BB), blk, 0, stream>>>(
      hcat, 512*NP, nullptr,0, nullptr,0, fuse_w,512, nullptr,0, fuse_g,fuse_b,
      fuse_out, 1024*NP, 1024, 512);

  k_maxavg<<<dim3(1024, BB), blk, 0, stream>>>(fuse_out, xm, xa);
  k_cls<<<dim3(1), dim3(128), 0, stream>>>(cls_lab, label_w, label_g, label_b, clsf);
  k_gbias<<<dim3(512, BB), blk, 0, stream>>>(c1_w, xm, xa, clsf, c1_b, gb);

  k_gemm<1,false,false,true,false><<<dim3(16,16,BB), blk, 0, stream>>>(
      fuse_out, 1024*NP, nullptr,0, nullptr,0, c1_w,3136, gb,512, bns1_g,bns1_b,
      out1, 512*NP, 512, 1024);

  k_gemm<1,false,false,true,false><<<dim3(16,8,BB), blk, 0, stream>>>(
      out1, 512*NP, nullptr,0, nullptr,0, c2_w,512, c2_b,0, bns2_g,bns2_b,
      out2, 256*NP, 256, 512);

  k_gemm<0,false,false,false,false><<<dim3(16,2,BB), blk, 0, stream>>>(
      out2, 256*NP, nullptr,0, nullptr,0, c3_w,256, c3_b,0, nullptr,nullptr,
      outp, 50*NP, 50, 256);
}

// Round 4
// 650.774 us; speedup vs baseline: 7.5195x; 2.5272x over previous
//
#include <hip/hip_runtime.h>

#define NP 4096
#define BB 2

typedef __attribute__((ext_vector_type(8))) short short8;
typedef __attribute__((ext_vector_type(4))) float f32x4;
#define MFMA_BF16 __builtin_amdgcn_mfma_f32_16x16x32_bf16

__device__ __forceinline__ float wsum(float v){
  #pragma unroll
  for (int o = 32; o; o >>= 1) v += __shfl_down(v, o, 64);
  return v;
}
__device__ __forceinline__ unsigned short f2bf(float x){
  unsigned int u = __float_as_uint(x);
  return (unsigned short)((u + 0x7fffu + ((u >> 16) & 1u)) >> 16);
}
__device__ __forceinline__ float bfh(unsigned short h){
  return __uint_as_float((unsigned int)h << 16);
}
__device__ __forceinline__ float bf2f(unsigned short h, unsigned short l){
  return bfh(h) + bfh(l);
}
__device__ __forceinline__ short8 ld8(const unsigned short* p){
  return *(const short8*)p;
}

// ---------------------------------------------------------------------------
// conv1: [128,3] x x[B,N,3] -> h0 nT hi/lo [B][N][128], bn+relu
__global__ __launch_bounds__(256) void k_conv1(
    const float* __restrict__ x, const float* __restrict__ w,
    const float* __restrict__ g, const float* __restrict__ bb,
    unsigned short* __restrict__ h0h, unsigned short* __restrict__ h0l)
{
  const int n = blockIdx.x * 256 + threadIdx.x;
  const int b = blockIdx.y;
  const float x0 = x[((size_t)b * NP + n) * 3 + 0];
  const float x1 = x[((size_t)b * NP + n) * 3 + 1];
  const float x2 = x[((size_t)b * NP + n) * 3 + 2];
  const size_t base = ((size_t)b * NP + n) * 128;
  for (int oc = 0; oc < 128; oc += 8) {
    short8 vh, vl;
    #pragma unroll
    for (int j = 0; j < 8; ++j) {
      const int o = oc + j;
      float v = w[o*3]*x0 + w[o*3+1]*x1 + w[o*3+2]*x2;
      v = v * (g[o] * rsqrtf(1.f + 1e-5f)) + bb[o];
      v = fmaxf(v, 0.f);
      const unsigned short hh = f2bf(v);
      vh[j] = (short)hh;
      vl[j] = (short)f2bf(v - bfh(hh));
    }
    *(short8*)&h0h[base + oc] = vh;
    *(short8*)&h0l[base + oc] = vl;
  }
}

// ---------------------------------------------------------------------------
// MFMA GEMM: out[b,o,n] = act(bn( sum_c W[o,c]*A[b,n,c] + convb )) (+res)
// A is bf16 hi/lo nT layout [N][ldA]. W fp32 [O][ldW], hi/lo split into LDS.
// Outputs: nT hi/lo (Onh/Onl, [N][ldON]) and/or CN (Ocn: fp32 or bf16 [O][NP]).
// Block: 256 thr = 4 waves; tile 64 o x 128 n; wave w owns 32 n.
template<int ACT, bool BN, bool RES, bool CNBF>
__global__ __launch_bounds__(256) void k_mm(
    const unsigned short* __restrict__ Ah, const unsigned short* __restrict__ Al,
    int ldA, size_t A_bs,
    const float* __restrict__ W, int ldW,
    const float* __restrict__ convb, int convb_bs,
    const float* __restrict__ bng, const float* __restrict__ bnb,
    const unsigned short* __restrict__ Rh, const unsigned short* __restrict__ Rl,
    int ldR, size_t R_bs,
    unsigned short* __restrict__ Onh, unsigned short* __restrict__ Onl,
    int ldON, size_t ON_bs,
    float* __restrict__ Ocn, size_t OCN_bs,
    int O, int Cin)
{
  const int o0 = blockIdx.x * 64;
  const int n0 = blockIdx.y * 128;
  const int b  = blockIdx.z;
  const int tid = threadIdx.x;
  const int w = tid >> 6, lane = tid & 63, lo = lane & 15, hi = lane >> 4;

  __shared__ __align__(16) unsigned short lWh[64 * 64];
  __shared__ __align__(16) unsigned short lWl[64 * 64];

  const unsigned short* Ahb = Ah + (size_t)b * A_bs;
  const unsigned short* Alb = Al + (size_t)b * A_bs;

  f32x4 acc[2][4];
  #pragma unroll
  for (int nf = 0; nf < 2; ++nf)
    #pragma unroll
    for (int of = 0; of < 4; ++of) acc[nf][of] = (f32x4){0.f,0.f,0.f,0.f};

  const int nw = n0 + w * 32;
  const int so = tid & 63;          // staging: o-row
  const int sq = tid >> 6;          // staging: chunk base

  for (int c0 = 0; c0 < Cin; c0 += 64) {
    __syncthreads();
    // ---- stage W[o0..o0+63][c0..c0+63] as bf16 hi/lo, XOR-swizzled chunks of 8
    #pragma unroll
    for (int p = 0; p < 2; ++p) {
      const int q8 = sq + p * 4;           // 0..7
      const int c = q8 * 8;
      float wv[8];
      if (o0 + so < O) {
        const float* wp = W + (size_t)(o0 + so) * ldW + c0 + c;
        const float4 w0 = *(const float4*)wp;
        const float4 w1 = *(const float4*)(wp + 4);
        wv[0]=w0.x; wv[1]=w0.y; wv[2]=w0.z; wv[3]=w0.w;
        wv[4]=w1.x; wv[5]=w1.y; wv[6]=w1.z; wv[7]=w1.w;
      } else {
        #pragma unroll
        for (int j = 0; j < 8; ++j) wv[j] = 0.f;
      }
      short8 vh, vl;
      #pragma unroll
      for (int j = 0; j < 8; ++j) {
        const unsigned short hh = f2bf(wv[j]);
        vh[j] = (short)hh;
        vl[j] = (short)f2bf(wv[j] - bfh(hh));
      }
      const int qs = q8 ^ (so & 7);
      *(short8*)&lWh[so * 64 + qs * 8] = vh;
      *(short8*)&lWl[so * 64 + qs * 8] = vl;
    }
    __syncthreads();
    // ---- two K=32 MFMA sub-steps
    #pragma unroll
    for (int ks = 0; ks < 2; ++ks) {
      short8 ah[2], al[2];
      #pragma unroll
      for (int nf = 0; nf < 2; ++nf) {
        const int n = nw + nf * 16 + lo;
        const size_t idx = (size_t)n * ldA + c0 + ks * 32 + hi * 8;
        ah[nf] = ld8(Ahb + idx);
        al[nf] = ld8(Alb + idx);
      }
      #pragma unroll
      for (int of = 0; of < 4; ++of) {
        const int row = of * 16 + lo;
        const int qs = (ks * 4 + hi) ^ (row & 7);
        const short8 bh = ld8(&lWh[row * 64 + qs * 8]);
        const short8 bl = ld8(&lWl[row * 64 + qs * 8]);
        #pragma unroll
        for (int nf = 0; nf < 2; ++nf) {
          acc[nf][of] = MFMA_BF16(ah[nf], bh, acc[nf][of], 0, 0, 0);
          acc[nf][of] = MFMA_BF16(ah[nf], bl, acc[nf][of], 0, 0, 0);
          acc[nf][of] = MFMA_BF16(al[nf], bh, acc[nf][of], 0, 0, 0);
        }
      }
    }
  }
  // ---- epilogue: D[n][o]; lane: col o = of*16+lo, row n = nw+nf*16+hi*4+r
  #pragma unroll
  for (int of = 0; of < 4; ++of) {
    const int o = o0 + of * 16 + lo;
    if (o < O) {
      const float cb = convb ? convb[(size_t)b * convb_bs + o] : 0.f;
      float sg = 0.f, sb = 0.f;
      if (BN) { sg = bng[o] * rsqrtf(1.f + 1e-5f); sb = bnb[o]; }
      #pragma unroll
      for (int nf = 0; nf < 2; ++nf) {
        #pragma unroll
        for (int r = 0; r < 4; ++r) {
          const int n = nw + nf * 16 + hi * 4 + r;
          float v = acc[nf][of][r] + cb;
          if (BN) v = v * sg + sb;
          if (ACT == 1) v = fmaxf(v, 0.f);
          if (ACT == 2) v = v > 0.f ? v : 0.2f * v;
          if (RES) v += bf2f(Rh[(size_t)b * R_bs + (size_t)n * ldR + o],
                             Rl[(size_t)b * R_bs + (size_t)n * ldR + o]);
          if (Onh) {
            const unsigned short hh = f2bf(v);
            Onh[(size_t)b * ON_bs + (size_t)n * ldON + o] = hh;
            Onl[(size_t)b * ON_bs + (size_t)n * ldON + o] = f2bf(v - bfh(hh));
          }
          if (Ocn) {
            if (CNBF) ((unsigned short*)Ocn)[(size_t)b * OCN_bs + (size_t)o * NP + n] = f2bf(v);
            else      Ocn[(size_t)b * OCN_bs + (size_t)o * NP + n] = v;
          }
        }
      }
    }
  }
}

// ---------------------------------------------------------------------------
// pass A (MFMA): column stats of symmetric E = Q^T Q.
__global__ __launch_bounds__(256) void k_passA(
    const unsigned short* __restrict__ qh, const unsigned short* __restrict__ ql,
    float* __restrict__ pmax, float* __restrict__ psum)
{
  const int m0 = blockIdx.x * 64;
  const int ns = blockIdx.y;
  const int b  = blockIdx.z;
  const int tid = threadIdx.x;
  const int w = tid >> 6, lane = tid & 63, lo = lane & 15, hi = lane >> 4;
  const unsigned short* qhb = qh + (size_t)b * NP * 32;
  const unsigned short* qlb = ql + (size_t)b * NP * 32;

  short8 bh[4], bl[4];
  #pragma unroll
  for (int fj = 0; fj < 4; ++fj) {
    const int m = m0 + fj * 16 + lo;
    bh[fj] = ld8(qhb + (size_t)m * 32 + hi * 8);
    bl[fj] = ld8(qlb + (size_t)m * 32 + hi * 8);
  }
  float mx[4], sm[4];
  #pragma unroll
  for (int fj = 0; fj < 4; ++fj) { mx[fj] = -3e38f; sm[fj] = 0.f; }

  const int nbeg = ns * 512;
  for (int ch = 0; ch < 8; ++ch) {
    const int n0 = nbeg + ch * 64;
    const int nr = n0 + w * 16 + lo;
    const short8 ah = ld8(qhb + (size_t)nr * 32 + hi * 8);
    const short8 al = ld8(qlb + (size_t)nr * 32 + hi * 8);
    #pragma unroll
    for (int fj = 0; fj < 4; ++fj) {
      f32x4 e = MFMA_BF16(ah, bh[fj], (f32x4){0.f,0.f,0.f,0.f}, 0, 0, 0);
      e = MFMA_BF16(ah, bl[fj], e, 0, 0, 0);
      e = MFMA_BF16(al, bh[fj], e, 0, 0, 0);
      const float lm = fmaxf(fmaxf(e[0], e[1]), fmaxf(e[2], e[3]));
      const float nm = fmaxf(mx[fj], lm);
      sm[fj] = sm[fj] * __expf(mx[fj] - nm)
             + __expf(e[0]-nm) + __expf(e[1]-nm) + __expf(e[2]-nm) + __expf(e[3]-nm);
      mx[fj] = nm;
    }
  }
  #pragma unroll
  for (int fj = 0; fj < 4; ++fj) {
    #pragma unroll
    for (int off = 16; off <= 32; off <<= 1) {
      const float om = __shfl_down(mx[fj], off, 64);
      const float os = __shfl_down(sm[fj], off, 64);
      const float nm = fmaxf(mx[fj], om);
      sm[fj] = sm[fj] * __expf(mx[fj] - nm) + os * __expf(om - nm);
      mx[fj] = nm;
    }
  }
  __shared__ float wmx[4][64], wsm[4][64];
  if (hi == 0) {
    #pragma unroll
    for (int fj = 0; fj < 4; ++fj) {
      wmx[w][fj * 16 + lo] = mx[fj];
      wsm[w][fj * 16 + lo] = sm[fj];
    }
  }
  __syncthreads();
  if (tid < 64) {
    float fm = wmx[0][tid], fs = wsm[0][tid];
    #pragma unroll
    for (int w2 = 1; w2 < 4; ++w2) {
      const float om = wmx[w2][tid], os = wsm[w2][tid];
      const float nm = fmaxf(fm, om);
      fs = fs * __expf(fm - nm) + os * __expf(om - nm);
      fm = nm;
    }
    pmax[((size_t)b * 8 + ns) * NP + m0 + tid] = fm;
    psum[((size_t)b * 8 + ns) * NP + m0 + tid] = fs;
  }
}

__global__ __launch_bounds__(256) void k_combineA(
    const float* __restrict__ pmax, const float* __restrict__ psum,
    float* __restrict__ rmax, float* __restrict__ rinv)
{
  const int i = blockIdx.x * 256 + threadIdx.x;   // < B*NP
  const int n = i & (NP - 1);
  const int b = i >> 12;
  float mx = -3e38f;
  #pragma unroll
  for (int s = 0; s < 8; ++s) mx = fmaxf(mx, pmax[((size_t)b*8 + s) * NP + n]);
  float sm = 0.f;
  #pragma unroll
  for (int s = 0; s < 8; ++s)
    sm += psum[((size_t)b*8 + s) * NP + n] * __expf(pmax[((size_t)b*8 + s) * NP + n] - mx);
  rmax[i] = mx;
  rinv[i] = 1.f / sm;
}

// ---------------------------------------------------------------------------
// pass B (MFMA): ypart[ns][m][c] = sum_n V[c,n]*P[n,m]; csp[ns][m] = colsum.
__global__ __launch_bounds__(256) void k_passB(
    const unsigned short* __restrict__ qh, const unsigned short* __restrict__ ql,
    const unsigned short* __restrict__ vbf,
    const float* __restrict__ rmax, const float* __restrict__ rinv,
    float* __restrict__ ypart, float* __restrict__ csp)
{
  const int m0 = blockIdx.x * 64;
  const int ns = blockIdx.y;
  const int b  = blockIdx.z;
  const int tid = threadIdx.x;
  const int w = tid >> 6, lane = tid & 63, lo = lane & 15, hi = lane >> 4;
  const unsigned short* qhb = qh + (size_t)b * NP * 32;
  const unsigned short* qlb = ql + (size_t)b * NP * 32;
  const unsigned short* vbb = vbf + (size_t)b * 128 * NP;

  __shared__ __align__(16) unsigned short Pt[2][64 * 64];
  __shared__ float csred[4][64];

  short8 bh[4], bl[4];
  #pragma unroll
  for (int fj = 0; fj < 4; ++fj) {
    const int m = m0 + fj * 16 + lo;
    bh[fj] = ld8(qhb + (size_t)m * 32 + hi * 8);
    bl[fj] = ld8(qlb + (size_t)m * 32 + hi * 8);
  }
  f32x4 yacc[2][4];
  #pragma unroll
  for (int cf = 0; cf < 2; ++cf)
    #pragma unroll
    for (int fj = 0; fj < 4; ++fj) yacc[cf][fj] = (f32x4){0.f,0.f,0.f,0.f};
  float cs[4] = {0.f, 0.f, 0.f, 0.f};

  const int swz = (lo & 7) << 3;
  const int c0 = w * 32;
  const int nbeg = ns * 1024;
  for (int ch = 0; ch < 16; ++ch) {
    unsigned short* Ptc = &Pt[ch & 1][0];
    const int n0 = nbeg + ch * 64;
    const int nr = n0 + w * 16 + lo;
    const short8 ah = ld8(qhb + (size_t)nr * 32 + hi * 8);
    const short8 al = ld8(qlb + (size_t)nr * 32 + hi * 8);
    f32x4 e[4];
    #pragma unroll
    for (int fj = 0; fj < 4; ++fj) {
      e[fj] = MFMA_BF16(ah, bh[fj], (f32x4){0.f,0.f,0.f,0.f}, 0, 0, 0);
      e[fj] = MFMA_BF16(ah, bl[fj], e[fj], 0, 0, 0);
      e[fj] = MFMA_BF16(al, bh[fj], e[fj], 0, 0, 0);
    }
    float rmv[4], riv[4];
    #pragma unroll
    for (int r = 0; r < 4; ++r) {
      const int n = n0 + w * 16 + hi * 4 + r;
      rmv[r] = rmax[(size_t)b * NP + n];
      riv[r] = rinv[(size_t)b * NP + n];
    }
    #pragma unroll
    for (int fj = 0; fj < 4; ++fj) {
      float p[4];
      #pragma unroll
      for (int r = 0; r < 4; ++r) p[r] = __expf(e[fj][r] - rmv[r]) * riv[r];
      cs[fj] += p[0] + p[1] + p[2] + p[3];
      ushort4 pk;
      pk.x = f2bf(p[0]); pk.y = f2bf(p[1]); pk.z = f2bf(p[2]); pk.w = f2bf(p[3]);
      const int row = fj * 16 + lo;
      const int col = (w * 16 + hi * 4) ^ swz;
      *(ushort4*)&Ptc[row * 64 + col] = pk;
    }
    short8 vfrag[2][2];
    #pragma unroll
    for (int cf = 0; cf < 2; ++cf)
      #pragma unroll
      for (int ks = 0; ks < 2; ++ks)
        vfrag[cf][ks] = ld8(vbb + (size_t)(c0 + cf*16 + lo) * NP + n0 + ks*32 + hi*8);
    __syncthreads();
    #pragma unroll
    for (int ks = 0; ks < 2; ++ks) {
      #pragma unroll
      for (int fj = 0; fj < 4; ++fj) {
        const int row = fj * 16 + lo;
        const int col = (ks * 32 + hi * 8) ^ swz;
        const short8 pf = ld8(&Ptc[row * 64 + col]);
        #pragma unroll
        for (int cf = 0; cf < 2; ++cf)
          yacc[cf][fj] = MFMA_BF16(vfrag[cf][ks], pf, yacc[cf][fj], 0, 0, 0);
      }
    }
  }
  // ---- write Y partials: ypart[(b*4+ns)*NP + m][c], float4 per fragment row
  float* yp = ypart + ((size_t)b * 4 + ns) * NP * 128;
  #pragma unroll
  for (int cf = 0; cf < 2; ++cf)
    #pragma unroll
    for (int fj = 0; fj < 4; ++fj) {
      const int m = m0 + fj * 16 + lo;
      const int c = w * 32 + cf * 16 + hi * 4;
      *(f32x4*)&yp[(size_t)m * 128 + c] = yacc[cf][fj];
    }
  #pragma unroll
  for (int fj = 0; fj < 4; ++fj) {
    cs[fj] += __shfl_down(cs[fj], 16, 64);
    cs[fj] += __shfl_down(cs[fj], 32, 64);
  }
  __syncthreads();
  if (hi == 0) {
    #pragma unroll
    for (int fj = 0; fj < 4; ++fj) csred[w][fj * 16 + lo] = cs[fj];
  }
  __syncthreads();
  if (tid < 64)
    csp[((size_t)b * 4 + ns) * NP + m0 + tid] =
        csred[0][tid] + csred[1][tid] + csred[2][tid] + csred[3][tid];
}

// combineB: d = h - (sum_ns y)/(1e-9 + sum_ns cs), emitted as nT hi/lo [N][128]
__global__ __launch_bounds__(256) void k_combineB(
    const float* __restrict__ ypart, const float* __restrict__ csp,
    const unsigned short* __restrict__ hinh, const unsigned short* __restrict__ hinl,
    int ldH, size_t H_bs,
    unsigned short* __restrict__ dh, unsigned short* __restrict__ dl)
{
  const size_t i = (size_t)blockIdx.x * 256 + threadIdx.x;  // < B*NP*128
  const int c = (int)(i & 127);
  const int n = (int)((i >> 7) & (NP - 1));
  const int b = (int)(i >> 19);
  float s = 1e-9f, y = 0.f;
  #pragma unroll
  for (int ns = 0; ns < 4; ++ns) {
    y += ypart[(((size_t)b*4 + ns) * NP + n) * 128 + c];
    s += csp[((size_t)b*4 + ns) * NP + n];
  }
  const float h = bf2f(hinh[(size_t)b * H_bs + (size_t)n * ldH + c],
                       hinl[(size_t)b * H_bs + (size_t)n * ldH + c]);
  const float d = h - y / s;
  const unsigned short hh = f2bf(d);
  dh[i] = hh;
  dl[i] = f2bf(d - bfh(hh));
}

// ---------------------------------------------------------------------------
// per-channel max/mean of fuse output in nT layout [N][1024]. grid (16, B)
__global__ __launch_bounds__(256) void k_maxavg_nt(
    const unsigned short* __restrict__ fh, const unsigned short* __restrict__ fl,
    float* __restrict__ xm, float* __restrict__ xa)
{
  const int tid = threadIdx.x;
  const int c4 = (tid & 15) * 4;
  const int st = tid >> 4;           // 16 n-stripes
  const int o0 = blockIdx.x * 64;
  const int b = blockIdx.y;
  const unsigned short* fhb = fh + (size_t)b * NP * 1024 + o0 + c4;
  const unsigned short* flb = fl + (size_t)b * NP * 1024 + o0 + c4;
  float mx[4] = {-3e38f,-3e38f,-3e38f,-3e38f}, sm[4] = {0.f,0.f,0.f,0.f};
  for (int n = st; n < NP; n += 16) {
    const ushort4 vh = *(const ushort4*)(fhb + (size_t)n * 1024);
    const ushort4 vl = *(const ushort4*)(flb + (size_t)n * 1024);
    const float v0 = bf2f(vh.x, vl.x), v1 = bf2f(vh.y, vl.y);
    const float v2 = bf2f(vh.z, vl.z), v3 = bf2f(vh.w, vl.w);
    mx[0] = fmaxf(mx[0], v0); sm[0] += v0;
    mx[1] = fmaxf(mx[1], v1); sm[1] += v1;
    mx[2] = fmaxf(mx[2], v2); sm[2] += v2;
    mx[3] = fmaxf(mx[3], v3); sm[3] += v3;
  }
  __shared__ float smx[16][64], ssm[16][64];
  #pragma unroll
  for (int j = 0; j < 4; ++j) { smx[st][c4 + j] = mx[j]; ssm[st][c4 + j] = sm[j]; }
  __syncthreads();
  if (tid < 64) {
    float m = -3e38f, s = 0.f;
    #pragma unroll
    for (int k = 0; k < 16; ++k) { m = fmaxf(m, smx[k][tid]); s += ssm[k][tid]; }
    xm[b * 1024 + o0 + tid] = m;
    xa[b * 1024 + o0 + tid] = s * (1.f / NP);
  }
}

__global__ void k_cls(const float* __restrict__ cl, const float* __restrict__ W,
                      const float* __restrict__ g, const float* __restrict__ bb,
                      float* __restrict__ clsf)
{
  const int t = threadIdx.x;
  const int b = t >> 6, o = t & 63;
  float a = 0.f;
  #pragma unroll
  for (int j = 0; j < 16; ++j) a += W[o * 16 + j] * cl[b * 16 + j];
  a = a * (g[o] * rsqrtf(1.f + 1e-5f)) + bb[o];
  clsf[b * 64 + o] = a > 0.f ? a : 0.2f * a;
}

__global__ __launch_bounds__(256) void k_gbias(
    const float* __restrict__ W1, const float* __restrict__ xm,
    const float* __restrict__ xa, const float* __restrict__ clsf,
    const float* __restrict__ c1b, float* __restrict__ gb)
{
  const int o = blockIdx.x, b = blockIdx.y;
  float a = 0.f;
  for (int j = threadIdx.x; j < 2112; j += 256) {
    const float gv = (j < 1024) ? xm[b * 1024 + j]
                   : (j < 2048) ? xa[b * 1024 + (j - 1024)]
                                : clsf[b * 64 + (j - 2048)];
    a += W1[(size_t)o * 3136 + 1024 + j] * gv;
  }
  a = wsum(a);
  __shared__ float red[4];
  const int w = threadIdx.x >> 6;
  if ((threadIdx.x & 63) == 0) red[w] = a;
  __syncthreads();
  if (threadIdx.x == 0) gb[b * 512 + o] = red[0] + red[1] + red[2] + red[3] + c1b[o];
}

// ---------------------------------------------------------------------------
extern "C" void kernel_launch(void* const* d_in, const int* in_sizes, int n_in,
                              void* d_out, int out_size, void* d_ws, size_t ws_size,
                              hipStream_t stream)
{
  const float* x        = (const float*)d_in[0];
  const float* cls_lab  = (const float*)d_in[1];
  const float* conv1_w  = (const float*)d_in[2];
  const float* bn1_g    = (const float*)d_in[3];
  const float* bn1_b    = (const float*)d_in[4];
  const float* conv2_w  = (const float*)d_in[5];
  const float* bn2_g    = (const float*)d_in[6];
  const float* bn2_b    = (const float*)d_in[7];
  const float* sa_qk_w  = (const float*)d_in[8];
  const float* sa_v_w   = (const float*)d_in[9];
  const float* sa_v_b   = (const float*)d_in[10];
  const float* sa_t_w   = (const float*)d_in[11];
  const float* sa_t_b   = (const float*)d_in[12];
  const float* sa_bn_g  = (const float*)d_in[13];
  const float* sa_bn_b  = (const float*)d_in[14];
  const float* fuse_w   = (const float*)d_in[15];
  const float* fuse_g   = (const float*)d_in[16];
  const float* fuse_b   = (const float*)d_in[17];
  const float* label_w  = (const float*)d_in[18];
  const float* label_g  = (const float*)d_in[19];
  const float* label_b  = (const float*)d_in[20];
  const float* c1_w     = (const float*)d_in[21];
  const float* c1_b     = (const float*)d_in[22];
  const float* bns1_g   = (const float*)d_in[23];
  const float* bns1_b   = (const float*)d_in[24];
  const float* c2_w     = (const float*)d_in[25];
  const float* c2_b     = (const float*)d_in[26];
  const float* bns2_g   = (const float*)d_in[27];
  const float* bns2_b   = (const float*)d_in[28];
  const float* c3_w     = (const float*)d_in[29];
  const float* c3_b     = (const float*)d_in[30];
  float* outp = (float*)d_out;

  float* f = (float*)d_ws;
  size_t off = 0;
  auto us = [&](size_t n_ushort) { unsigned short* p = (unsigned short*)(f + off);
                                   off += (n_ushort + 1) / 2; return p; };
  unsigned short* h0h  = us((size_t)BB*NP*128);
  unsigned short* h0l  = us((size_t)BB*NP*128);
  unsigned short* h1h  = us((size_t)BB*NP*128);
  unsigned short* h1l  = us((size_t)BB*NP*128);
  unsigned short* hch  = us((size_t)BB*NP*512);
  unsigned short* hcl  = us((size_t)BB*NP*512);
  unsigned short* qTh  = us((size_t)BB*NP*32);
  unsigned short* qTl  = us((size_t)BB*NP*32);
  unsigned short* vb   = us((size_t)BB*128*NP);
  unsigned short* dhб  = us((size_t)BB*NP*128);
  unsigned short* dlб  = us((size_t)BB*NP*128);
  float* pmax  = f + off; off += (size_t)BB*8*NP;
  float* psum  = f + off; off += (size_t)BB*8*NP;
  float* rmaxb = f + off; off += (size_t)BB*NP;
  float* rinvb = f + off; off += (size_t)BB*NP;
  float* csp   = f + off; off += (size_t)BB*4*NP;
  float* xm    = f + off; off += (size_t)BB*1024;
  float* xa    = f + off; off += (size_t)BB*1024;
  float* clsf  = f + off; off += (size_t)BB*64;
  float* gb    = f + off; off += (size_t)BB*512;
  off = (off + 255) & ~(size_t)255;
  float* ypart = f + off;                               // BB*4*NP*128 floats
  unsigned short* fuh = (unsigned short*)ypart;         // alias: fuse nT (after ypart dead)
  unsigned short* ful = fuh + (size_t)BB*NP*1024;
  unsigned short* o1h = ful + (size_t)BB*NP*1024;
  unsigned short* o1l = o1h + (size_t)BB*NP*512;
  unsigned short* o2h = o1l + (size_t)BB*NP*512;
  unsigned short* o2l = o2h + (size_t)BB*NP*256;

  const dim3 blk(256);

  k_conv1<<<dim3(16, BB), blk, 0, stream>>>(x, conv1_w, bn1_g, bn1_b, h0h, h0l);

  // conv2: 128<-128, bn+relu -> h1 nT
  k_mm<1,true,false,false><<<dim3(2,32,BB), blk, 0, stream>>>(
      h0h, h0l, 128, (size_t)NP*128, conv2_w, 128, nullptr, 0, bn2_g, bn2_b,
      nullptr, nullptr, 0, 0, h1h, h1l, 128, (size_t)NP*128, nullptr, 0, 128, 128);

  for (int i = 0; i < 4; ++i) {
    const unsigned short* hinh = (i == 0) ? h1h : hch + (size_t)(i-1)*128;
    const unsigned short* hinl = (i == 0) ? h1l : hcl + (size_t)(i-1)*128;
    const int ldH = (i == 0) ? 128 : 512;
    const size_t H_bs = (size_t)NP * ldH;

    // q: 32<-128 -> qT nT hi/lo
    k_mm<0,false,false,false><<<dim3(1,32,BB), blk, 0, stream>>>(
        hinh, hinl, ldH, H_bs, sa_qk_w + (size_t)i*32*128, 128, nullptr, 0,
        nullptr, nullptr, nullptr, nullptr, 0, 0,
        qTh, qTl, 32, (size_t)NP*32, nullptr, 0, 32, 128);

    // v: 128<-128 + v_b -> bf16 [C][N]
    k_mm<0,false,false,true><<<dim3(2,32,BB), blk, 0, stream>>>(
        hinh, hinl, ldH, H_bs, sa_v_w + (size_t)i*128*128, 128,
        sa_v_b + (size_t)i*128, 0, nullptr, nullptr,
        nullptr, nullptr, 0, 0, nullptr, nullptr, 0, 0,
        (float*)vb, (size_t)128*NP, 128, 128);

    k_passA<<<dim3(64,8,BB), blk, 0, stream>>>(qTh, qTl, pmax, psum);
    k_combineA<<<dim3(BB*NP/256), blk, 0, stream>>>(pmax, psum, rmaxb, rinvb);
    k_passB<<<dim3(64,4,BB), blk, 0, stream>>>(qTh, qTl, vb, rmaxb, rinvb, ypart, csp);
    k_combineB<<<dim3(BB*NP*128/256), blk, 0, stream>>>(
        ypart, csp, hinh, hinl, ldH, H_bs, dhб, dlб);

    // t: 128<-128 on (h - x_r), + t_b, bn, relu, + residual h -> hcat slice nT
    k_mm<1,true,true,false><<<dim3(2,32,BB), blk, 0, stream>>>(
        dhб, dlб, 128, (size_t)NP*128, sa_t_w + (size_t)i*128*128, 128,
        sa_t_b + (size_t)i*128, 0, sa_bn_g + (size_t)i*128, sa_bn_b + (size_t)i*128,
        hinh, hinl, ldH, H_bs,
        hch + (size_t)i*128, hcl + (size_t)i*128, 512, (size_t)NP*512,
        nullptr, 0, 128, 128);
  }

  // fuse: 1024<-512, bn + leaky -> fuse nT
  k_mm<2,true,false,false><<<dim3(16,32,BB), blk, 0, stream>>>(
      hch, hcl, 512, (size_t)NP*512, fuse_w, 512, nullptr, 0, fuse_g, fuse_b,
      nullptr, nullptr, 0, 0, fuh, ful, 1024, (size_t)NP*1024, nullptr, 0, 1024, 512);

  k_maxavg_nt<<<dim3(16, BB), blk, 0, stream>>>(fuh, ful, xm, xa);
  k_cls<<<dim3(1), dim3(128), 0, stream>>>(cls_lab, label_w, label_g, label_b, clsf);
  k_gbias<<<dim3(512, BB), blk, 0, stream>>>(c1_w, xm, xa, clsf, c1_b, gb);

  // convs1: 512<-1024 (+gb per b,o), bn, relu -> out1 nT
  k_mm<1,true,false,false><<<dim3(8,32,BB), blk, 0, stream>>>(
      fuh, ful, 1024, (size_t)NP*1024, c1_w, 3136, gb, 512, bns1_g, bns1_b,
      nullptr, nullptr, 0, 0, o1h, o1l, 512, (size_t)NP*512, nullptr, 0, 512, 1024);

  // convs2: 256<-512 + c2_b, bn, relu -> out2 nT
  k_mm<1,true,false,false><<<dim3(4,32,BB), blk, 0, stream>>>(
      o1h, o1l, 512, (size_t)NP*512, c2_w, 512, c2_b, 0, bns2_g, bns2_b,
      nullptr, nullptr, 0, 0, o2h, o2l, 256, (size_t)NP*256, nullptr, 0, 256, 512);

  // convs3: 50<-256 + c3_b -> fp32 [50][N] output
  k_mm<0,false,false,false><<<dim3(1,32,BB), blk, 0, stream>>>(
      o2h, o2l, 256, (size_t)NP*256, c3_w, 256, c3_b, 0, nullptr, nullptr,
      nullptr, nullptr, 0, 0, nullptr, nullptr, 0, 0,
      outp, (size_t)50*NP, 50, 256);
}

// Round 5
// 565.286 us; speedup vs baseline: 8.6567x; 1.1512x over previous
//
#include <hip/hip_runtime.h>

#define NP 4096
#define BB 2

typedef __attribute__((ext_vector_type(8))) short short8;
typedef __attribute__((ext_vector_type(4))) float f32x4;
#define MFMA_BF16 __builtin_amdgcn_mfma_f32_16x16x32_bf16

__device__ __forceinline__ float wsum(float v){
  #pragma unroll
  for (int o = 32; o; o >>= 1) v += __shfl_down(v, o, 64);
  return v;
}
__device__ __forceinline__ unsigned short f2bf(float x){
  unsigned int u = __float_as_uint(x);
  return (unsigned short)((u + 0x7fffu + ((u >> 16) & 1u)) >> 16);
}
__device__ __forceinline__ float bfh(unsigned short h){
  return __uint_as_float((unsigned int)h << 16);
}
__device__ __forceinline__ float bf2f(unsigned short h, unsigned short l){
  return bfh(h) + bfh(l);
}
__device__ __forceinline__ short8 ld8(const unsigned short* p){
  return *(const short8*)p;
}

// ---------------------------------------------------------------------------
// conv1: [128,3] x x[B,N,3] -> h0 nT hi/lo [B][N][128], bn+relu
// grid (128, B): 32 n per block; thread owns (n, 16-channel group)
__global__ __launch_bounds__(256) void k_conv1(
    const float* __restrict__ x, const float* __restrict__ w,
    const float* __restrict__ g, const float* __restrict__ bb,
    unsigned short* __restrict__ h0h, unsigned short* __restrict__ h0l)
{
  const int tid = threadIdx.x;
  const int n = blockIdx.x * 32 + (tid >> 3);
  const int oc = (tid & 7) * 16;
  const int b = blockIdx.y;
  const float x0 = x[((size_t)b * NP + n) * 3 + 0];
  const float x1 = x[((size_t)b * NP + n) * 3 + 1];
  const float x2 = x[((size_t)b * NP + n) * 3 + 2];
  const size_t base = ((size_t)b * NP + n) * 128 + oc;
  #pragma unroll
  for (int half = 0; half < 2; ++half) {
    short8 vh, vl;
    #pragma unroll
    for (int j = 0; j < 8; ++j) {
      const int o = oc + half * 8 + j;
      float v = w[o*3]*x0 + w[o*3+1]*x1 + w[o*3+2]*x2;
      v = v * (g[o] * rsqrtf(1.f + 1e-5f)) + bb[o];
      v = fmaxf(v, 0.f);
      const unsigned short hh = f2bf(v);
      vh[j] = (short)hh;
      vl[j] = (short)f2bf(v - bfh(hh));
    }
    *(short8*)&h0h[base + half * 8] = vh;
    *(short8*)&h0l[base + half * 8] = vl;
  }
}

// ---------------------------------------------------------------------------
// MFMA GEMM: out[b,o,n] = act(bn( sum_c W[o,c]*A[b,n,c] + convb )) (+res)
// A is bf16 hi/lo nT layout [N][ldA]. W fp32 [O][ldW], hi/lo split into LDS.
// Outputs: nT hi/lo (Onh/Onl, [N][ldON]) and/or CN (Ocn: fp32 or bf16 [O][NP]).
// Block: 256 thr = 4 waves; tile 64 o x 128 n; wave w owns 32 n.
template<int ACT, bool BN, bool RES, bool CNBF>
__global__ __launch_bounds__(256) void k_mm(
    const unsigned short* __restrict__ Ah, const unsigned short* __restrict__ Al,
    int ldA, size_t A_bs,
    const float* __restrict__ W, int ldW,
    const float* __restrict__ convb, int convb_bs,
    const float* __restrict__ bng, const float* __restrict__ bnb,
    const unsigned short* __restrict__ Rh, const unsigned short* __restrict__ Rl,
    int ldR, size_t R_bs,
    unsigned short* __restrict__ Onh, unsigned short* __restrict__ Onl,
    int ldON, size_t ON_bs,
    float* __restrict__ Ocn, size_t OCN_bs,
    int O, int Cin)
{
  const int o0 = blockIdx.x * 64;
  const int n0 = blockIdx.y * 128;
  const int b  = blockIdx.z;
  const int tid = threadIdx.x;
  const int w = tid >> 6, lane = tid & 63, lo = lane & 15, hi = lane >> 4;

  __shared__ __align__(16) unsigned short lWh[64 * 64];
  __shared__ __align__(16) unsigned short lWl[64 * 64];

  const unsigned short* Ahb = Ah + (size_t)b * A_bs;
  const unsigned short* Alb = Al + (size_t)b * A_bs;

  f32x4 acc[2][4];
  #pragma unroll
  for (int nf = 0; nf < 2; ++nf)
    #pragma unroll
    for (int of = 0; of < 4; ++of) acc[nf][of] = (f32x4){0.f,0.f,0.f,0.f};

  const int nw = n0 + w * 32;
  const int so = tid & 63;          // staging: o-row
  const int sq = tid >> 6;          // staging: chunk base

  for (int c0 = 0; c0 < Cin; c0 += 64) {
    __syncthreads();
    // ---- stage W[o0..o0+63][c0..c0+63] as bf16 hi/lo, XOR-swizzled chunks of 8
    #pragma unroll
    for (int p = 0; p < 2; ++p) {
      const int q8 = sq + p * 4;           // 0..7
      const int c = q8 * 8;
      float wv[8];
      if (o0 + so < O) {
        const float* wp = W + (size_t)(o0 + so) * ldW + c0 + c;
        const float4 w0 = *(const float4*)wp;
        const float4 w1 = *(const float4*)(wp + 4);
        wv[0]=w0.x; wv[1]=w0.y; wv[2]=w0.z; wv[3]=w0.w;
        wv[4]=w1.x; wv[5]=w1.y; wv[6]=w1.z; wv[7]=w1.w;
      } else {
        #pragma unroll
        for (int j = 0; j < 8; ++j) wv[j] = 0.f;
      }
      short8 vh, vl;
      #pragma unroll
      for (int j = 0; j < 8; ++j) {
        const unsigned short hh = f2bf(wv[j]);
        vh[j] = (short)hh;
        vl[j] = (short)f2bf(wv[j] - bfh(hh));
      }
      const int qs = q8 ^ (so & 7);
      *(short8*)&lWh[so * 64 + qs * 8] = vh;
      *(short8*)&lWl[so * 64 + qs * 8] = vl;
    }
    __syncthreads();
    // ---- two K=32 MFMA sub-steps
    #pragma unroll
    for (int ks = 0; ks < 2; ++ks) {
      short8 ah[2], al[2];
      #pragma unroll
      for (int nf = 0; nf < 2; ++nf) {
        const int n = nw + nf * 16 + lo;
        const size_t idx = (size_t)n * ldA + c0 + ks * 32 + hi * 8;
        ah[nf] = ld8(Ahb + idx);
        al[nf] = ld8(Alb + idx);
      }
      #pragma unroll
      for (int of = 0; of < 4; ++of) {
        const int row = of * 16 + lo;
        const int qs = (ks * 4 + hi) ^ (row & 7);
        const short8 bh = ld8(&lWh[row * 64 + qs * 8]);
        const short8 bl = ld8(&lWl[row * 64 + qs * 8]);
        #pragma unroll
        for (int nf = 0; nf < 2; ++nf) {
          acc[nf][of] = MFMA_BF16(ah[nf], bh, acc[nf][of], 0, 0, 0);
          acc[nf][of] = MFMA_BF16(ah[nf], bl, acc[nf][of], 0, 0, 0);
          acc[nf][of] = MFMA_BF16(al[nf], bh, acc[nf][of], 0, 0, 0);
        }
      }
    }
  }
  // ---- epilogue: D[n][o]; lane: col o = of*16+lo, row n = nw+nf*16+hi*4+r
  #pragma unroll
  for (int of = 0; of < 4; ++of) {
    const int o = o0 + of * 16 + lo;
    if (o < O) {
      const float cb = convb ? convb[(size_t)b * convb_bs + o] : 0.f;
      float sg = 0.f, sb = 0.f;
      if (BN) { sg = bng[o] * rsqrtf(1.f + 1e-5f); sb = bnb[o]; }
      #pragma unroll
      for (int nf = 0; nf < 2; ++nf) {
        #pragma unroll
        for (int r = 0; r < 4; ++r) {
          const int n = nw + nf * 16 + hi * 4 + r;
          float v = acc[nf][of][r] + cb;
          if (BN) v = v * sg + sb;
          if (ACT == 1) v = fmaxf(v, 0.f);
          if (ACT == 2) v = v > 0.f ? v : 0.2f * v;
          if (RES) v += bf2f(Rh[(size_t)b * R_bs + (size_t)n * ldR + o],
                             Rl[(size_t)b * R_bs + (size_t)n * ldR + o]);
          if (Onh) {
            const unsigned short hh = f2bf(v);
            Onh[(size_t)b * ON_bs + (size_t)n * ldON + o] = hh;
            Onl[(size_t)b * ON_bs + (size_t)n * ldON + o] = f2bf(v - bfh(hh));
          }
          if (Ocn) {
            if (CNBF) ((unsigned short*)Ocn)[(size_t)b * OCN_bs + (size_t)o * NP + n] = f2bf(v);
            else      Ocn[(size_t)b * OCN_bs + (size_t)o * NP + n] = v;
          }
        }
      }
    }
  }
}

// ---------------------------------------------------------------------------
// pass A (MFMA): column stats of symmetric E = Q^T Q.
__global__ __launch_bounds__(256) void k_passA(
    const unsigned short* __restrict__ qh, const unsigned short* __restrict__ ql,
    float* __restrict__ pmax, float* __restrict__ psum)
{
  const int m0 = blockIdx.x * 64;
  const int ns = blockIdx.y;
  const int b  = blockIdx.z;
  const int tid = threadIdx.x;
  const int w = tid >> 6, lane = tid & 63, lo = lane & 15, hi = lane >> 4;
  const unsigned short* qhb = qh + (size_t)b * NP * 32;
  const unsigned short* qlb = ql + (size_t)b * NP * 32;

  short8 bh[4], bl[4];
  #pragma unroll
  for (int fj = 0; fj < 4; ++fj) {
    const int m = m0 + fj * 16 + lo;
    bh[fj] = ld8(qhb + (size_t)m * 32 + hi * 8);
    bl[fj] = ld8(qlb + (size_t)m * 32 + hi * 8);
  }
  float mx[4], sm[4];
  #pragma unroll
  for (int fj = 0; fj < 4; ++fj) { mx[fj] = -3e38f; sm[fj] = 0.f; }

  const int nbeg = ns * 512;
  for (int ch = 0; ch < 8; ++ch) {
    const int n0 = nbeg + ch * 64;
    const int nr = n0 + w * 16 + lo;
    const short8 ah = ld8(qhb + (size_t)nr * 32 + hi * 8);
    const short8 al = ld8(qlb + (size_t)nr * 32 + hi * 8);
    #pragma unroll
    for (int fj = 0; fj < 4; ++fj) {
      f32x4 e = MFMA_BF16(ah, bh[fj], (f32x4){0.f,0.f,0.f,0.f}, 0, 0, 0);
      e = MFMA_BF16(ah, bl[fj], e, 0, 0, 0);
      e = MFMA_BF16(al, bh[fj], e, 0, 0, 0);
      const float lm = fmaxf(fmaxf(e[0], e[1]), fmaxf(e[2], e[3]));
      const float nm = fmaxf(mx[fj], lm);
      sm[fj] = sm[fj] * __expf(mx[fj] - nm)
             + __expf(e[0]-nm) + __expf(e[1]-nm) + __expf(e[2]-nm) + __expf(e[3]-nm);
      mx[fj] = nm;
    }
  }
  #pragma unroll
  for (int fj = 0; fj < 4; ++fj) {
    #pragma unroll
    for (int off = 16; off <= 32; off <<= 1) {
      const float om = __shfl_down(mx[fj], off, 64);
      const float os = __shfl_down(sm[fj], off, 64);
      const float nm = fmaxf(mx[fj], om);
      sm[fj] = sm[fj] * __expf(mx[fj] - nm) + os * __expf(om - nm);
      mx[fj] = nm;
    }
  }
  __shared__ float wmx[4][64], wsm[4][64];
  if (hi == 0) {
    #pragma unroll
    for (int fj = 0; fj < 4; ++fj) {
      wmx[w][fj * 16 + lo] = mx[fj];
      wsm[w][fj * 16 + lo] = sm[fj];
    }
  }
  __syncthreads();
  if (tid < 64) {
    float fm = wmx[0][tid], fs = wsm[0][tid];
    #pragma unroll
    for (int w2 = 1; w2 < 4; ++w2) {
      const float om = wmx[w2][tid], os = wsm[w2][tid];
      const float nm = fmaxf(fm, om);
      fs = fs * __expf(fm - nm) + os * __expf(om - nm);
      fm = nm;
    }
    pmax[((size_t)b * 8 + ns) * NP + m0 + tid] = fm;
    psum[((size_t)b * 8 + ns) * NP + m0 + tid] = fs;
  }
}

__global__ __launch_bounds__(256) void k_combineA(
    const float* __restrict__ pmax, const float* __restrict__ psum,
    float* __restrict__ rmax, float* __restrict__ rinv)
{
  const int i = blockIdx.x * 256 + threadIdx.x;   // < B*NP
  const int n = i & (NP - 1);
  const int b = i >> 12;
  float mx = -3e38f;
  #pragma unroll
  for (int s = 0; s < 8; ++s) mx = fmaxf(mx, pmax[((size_t)b*8 + s) * NP + n]);
  float sm = 0.f;
  #pragma unroll
  for (int s = 0; s < 8; ++s)
    sm += psum[((size_t)b*8 + s) * NP + n] * __expf(pmax[((size_t)b*8 + s) * NP + n] - mx);
  rmax[i] = mx;
  rinv[i] = 1.f / sm;
}

// ---------------------------------------------------------------------------
// pass B (MFMA): ypart[ns][m][c] = sum_n V[c,n]*P[n,m]; csp[ns][m] = colsum.
__global__ __launch_bounds__(256) void k_passB(
    const unsigned short* __restrict__ qh, const unsigned short* __restrict__ ql,
    const unsigned short* __restrict__ vbf,
    const float* __restrict__ rmax, const float* __restrict__ rinv,
    float* __restrict__ ypart, float* __restrict__ csp)
{
  const int m0 = blockIdx.x * 64;
  const int ns = blockIdx.y;
  const int b  = blockIdx.z;
  const int tid = threadIdx.x;
  const int w = tid >> 6, lane = tid & 63, lo = lane & 15, hi = lane >> 4;
  const unsigned short* qhb = qh + (size_t)b * NP * 32;
  const unsigned short* qlb = ql + (size_t)b * NP * 32;
  const unsigned short* vbb = vbf + (size_t)b * 128 * NP;

  __shared__ __align__(16) unsigned short Pt[2][64 * 64];
  __shared__ float csred[4][64];

  short8 bh[4], bl[4];
  #pragma unroll
  for (int fj = 0; fj < 4; ++fj) {
    const int m = m0 + fj * 16 + lo;
    bh[fj] = ld8(qhb + (size_t)m * 32 + hi * 8);
    bl[fj] = ld8(qlb + (size_t)m * 32 + hi * 8);
  }
  f32x4 yacc[2][4];
  #pragma unroll
  for (int cf = 0; cf < 2; ++cf)
    #pragma unroll
    for (int fj = 0; fj < 4; ++fj) yacc[cf][fj] = (f32x4){0.f,0.f,0.f,0.f};
  float cs[4] = {0.f, 0.f, 0.f, 0.f};

  const int swz = (lo & 7) << 3;
  const int c0 = w * 32;
  const int nbeg = ns * 1024;
  for (int ch = 0; ch < 16; ++ch) {
    unsigned short* Ptc = &Pt[ch & 1][0];
    const int n0 = nbeg + ch * 64;
    const int nr = n0 + w * 16 + lo;
    const short8 ah = ld8(qhb + (size_t)nr * 32 + hi * 8);
    const short8 al = ld8(qlb + (size_t)nr * 32 + hi * 8);
    f32x4 e[4];
    #pragma unroll
    for (int fj = 0; fj < 4; ++fj) {
      e[fj] = MFMA_BF16(ah, bh[fj], (f32x4){0.f,0.f,0.f,0.f}, 0, 0, 0);
      e[fj] = MFMA_BF16(ah, bl[fj], e[fj], 0, 0, 0);
      e[fj] = MFMA_BF16(al, bh[fj], e[fj], 0, 0, 0);
    }
    float rmv[4], riv[4];
    #pragma unroll
    for (int r = 0; r < 4; ++r) {
      const int n = n0 + w * 16 + hi * 4 + r;
      rmv[r] = rmax[(size_t)b * NP + n];
      riv[r] = rinv[(size_t)b * NP + n];
    }
    #pragma unroll
    for (int fj = 0; fj < 4; ++fj) {
      float p[4];
      #pragma unroll
      for (int r = 0; r < 4; ++r) p[r] = __expf(e[fj][r] - rmv[r]) * riv[r];
      cs[fj] += p[0] + p[1] + p[2] + p[3];
      ushort4 pk;
      pk.x = f2bf(p[0]); pk.y = f2bf(p[1]); pk.z = f2bf(p[2]); pk.w = f2bf(p[3]);
      const int row = fj * 16 + lo;
      const int col = (w * 16 + hi * 4) ^ swz;
      *(ushort4*)&Ptc[row * 64 + col] = pk;
    }
    short8 vfrag[2][2];
    #pragma unroll
    for (int cf = 0; cf < 2; ++cf)
      #pragma unroll
      for (int ks = 0; ks < 2; ++ks)
        vfrag[cf][ks] = ld8(vbb + (size_t)(c0 + cf*16 + lo) * NP + n0 + ks*32 + hi*8);
    __syncthreads();
    #pragma unroll
    for (int ks = 0; ks < 2; ++ks) {
      #pragma unroll
      for (int fj = 0; fj < 4; ++fj) {
        const int row = fj * 16 + lo;
        const int col = (ks * 32 + hi * 8) ^ swz;
        const short8 pf = ld8(&Ptc[row * 64 + col]);
        #pragma unroll
        for (int cf = 0; cf < 2; ++cf)
          yacc[cf][fj] = MFMA_BF16(vfrag[cf][ks], pf, yacc[cf][fj], 0, 0, 0);
      }
    }
  }
  // ---- write Y partials: ypart[(b*4+ns)*NP + m][c], float4 per fragment row
  float* yp = ypart + ((size_t)b * 4 + ns) * NP * 128;
  #pragma unroll
  for (int cf = 0; cf < 2; ++cf)
    #pragma unroll
    for (int fj = 0; fj < 4; ++fj) {
      const int m = m0 + fj * 16 + lo;
      const int c = w * 32 + cf * 16 + hi * 4;
      *(f32x4*)&yp[(size_t)m * 128 + c] = yacc[cf][fj];
    }
  #pragma unroll
  for (int fj = 0; fj < 4; ++fj) {
    cs[fj] += __shfl_down(cs[fj], 16, 64);
    cs[fj] += __shfl_down(cs[fj], 32, 64);
  }
  __syncthreads();
  if (hi == 0) {
    #pragma unroll
    for (int fj = 0; fj < 4; ++fj) csred[w][fj * 16 + lo] = cs[fj];
  }
  __syncthreads();
  if (tid < 64)
    csp[((size_t)b * 4 + ns) * NP + m0 + tid] =
        csred[0][tid] + csred[1][tid] + csred[2][tid] + csred[3][tid];
}

// combineB: d = h - (sum_ns y)/(1e-9 + sum_ns cs), emitted as nT hi/lo [N][128]
__global__ __launch_bounds__(256) void k_combineB(
    const float* __restrict__ ypart, const float* __restrict__ csp,
    const unsigned short* __restrict__ hinh, const unsigned short* __restrict__ hinl,
    int ldH, size_t H_bs,
    unsigned short* __restrict__ dh, unsigned short* __restrict__ dl)
{
  const size_t i = (size_t)blockIdx.x * 256 + threadIdx.x;  // < B*NP*128
  const int c = (int)(i & 127);
  const int n = (int)((i >> 7) & (NP - 1));
  const int b = (int)(i >> 19);
  float s = 1e-9f, y = 0.f;
  #pragma unroll
  for (int ns = 0; ns < 4; ++ns) {
    y += ypart[(((size_t)b*4 + ns) * NP + n) * 128 + c];
    s += csp[((size_t)b*4 + ns) * NP + n];
  }
  const float h = bf2f(hinh[(size_t)b * H_bs + (size_t)n * ldH + c],
                       hinl[(size_t)b * H_bs + (size_t)n * ldH + c]);
  const float d = h - y / s;
  const unsigned short hh = f2bf(d);
  dh[i] = hh;
  dl[i] = f2bf(d - bfh(hh));
}

// ---------------------------------------------------------------------------
// per-channel max/mean of fuse output nT [N][1024] — stage 1 partials.
// grid (16 c-tiles, 16 n-splits, B)
__global__ __launch_bounds__(256) void k_maxavg_p(
    const unsigned short* __restrict__ fh, const unsigned short* __restrict__ fl,
    float* __restrict__ pmx, float* __restrict__ psm)
{
  const int tid = threadIdx.x;
  const int c4 = (tid & 15) * 4;
  const int st = tid >> 4;           // 16 n-stripes
  const int o0 = blockIdx.x * 64;
  const int nsp = blockIdx.y;
  const int b = blockIdx.z;
  const int nbeg = nsp * 256;
  const unsigned short* fhb = fh + (size_t)b * NP * 1024 + o0 + c4;
  const unsigned short* flb = fl + (size_t)b * NP * 1024 + o0 + c4;
  float mx[4] = {-3e38f,-3e38f,-3e38f,-3e38f}, sm[4] = {0.f,0.f,0.f,0.f};
  #pragma unroll 4
  for (int n = nbeg + st; n < nbeg + 256; n += 16) {
    const ushort4 vh = *(const ushort4*)(fhb + (size_t)n * 1024);
    const ushort4 vl = *(const ushort4*)(flb + (size_t)n * 1024);
    const float v0 = bf2f(vh.x, vl.x), v1 = bf2f(vh.y, vl.y);
    const float v2 = bf2f(vh.z, vl.z), v3 = bf2f(vh.w, vl.w);
    mx[0] = fmaxf(mx[0], v0); sm[0] += v0;
    mx[1] = fmaxf(mx[1], v1); sm[1] += v1;
    mx[2] = fmaxf(mx[2], v2); sm[2] += v2;
    mx[3] = fmaxf(mx[3], v3); sm[3] += v3;
  }
  __shared__ float smx[16][64], ssm[16][64];
  #pragma unroll
  for (int j = 0; j < 4; ++j) { smx[st][c4 + j] = mx[j]; ssm[st][c4 + j] = sm[j]; }
  __syncthreads();
  if (tid < 64) {
    float m = -3e38f, s = 0.f;
    #pragma unroll
    for (int k = 0; k < 16; ++k) { m = fmaxf(m, smx[k][tid]); s += ssm[k][tid]; }
    pmx[((size_t)b * 16 + nsp) * 1024 + o0 + tid] = m;
    psm[((size_t)b * 16 + nsp) * 1024 + o0 + tid] = s;
  }
}

// stage 2: combine 16 partials. grid (B*1024/256)
__global__ __launch_bounds__(256) void k_maxavg_c(
    const float* __restrict__ pmx, const float* __restrict__ psm,
    float* __restrict__ xm, float* __restrict__ xa)
{
  const int i = blockIdx.x * 256 + threadIdx.x;   // < B*1024
  const int c = i & 1023;
  const int b = i >> 10;
  float m = -3e38f, s = 0.f;
  #pragma unroll
  for (int k = 0; k < 16; ++k) {
    m = fmaxf(m, pmx[((size_t)b * 16 + k) * 1024 + c]);
    s += psm[((size_t)b * 16 + k) * 1024 + c];
  }
  xm[i] = m;
  xa[i] = s * (1.f / NP);
}

__global__ void k_cls(const float* __restrict__ cl, const float* __restrict__ W,
                      const float* __restrict__ g, const float* __restrict__ bb,
                      float* __restrict__ clsf)
{
  const int t = threadIdx.x;
  const int b = t >> 6, o = t & 63;
  float a = 0.f;
  #pragma unroll
  for (int j = 0; j < 16; ++j) a += W[o * 16 + j] * cl[b * 16 + j];
  a = a * (g[o] * rsqrtf(1.f + 1e-5f)) + bb[o];
  clsf[b * 64 + o] = a > 0.f ? a : 0.2f * a;
}

__global__ __launch_bounds__(256) void k_gbias(
    const float* __restrict__ W1, const float* __restrict__ xm,
    const float* __restrict__ xa, const float* __restrict__ clsf,
    const float* __restrict__ c1b, float* __restrict__ gb)
{
  const int o = blockIdx.x, b = blockIdx.y;
  float a = 0.f;
  for (int j = threadIdx.x; j < 2112; j += 256) {
    const float gv = (j < 1024) ? xm[b * 1024 + j]
                   : (j < 2048) ? xa[b * 1024 + (j - 1024)]
                                : clsf[b * 64 + (j - 2048)];
    a += W1[(size_t)o * 3136 + 1024 + j] * gv;
  }
  a = wsum(a);
  __shared__ float red[4];
  const int w = threadIdx.x >> 6;
  if ((threadIdx.x & 63) == 0) red[w] = a;
  __syncthreads();
  if (threadIdx.x == 0) gb[b * 512 + o] = red[0] + red[1] + red[2] + red[3] + c1b[o];
}

// ---------------------------------------------------------------------------
extern "C" void kernel_launch(void* const* d_in, const int* in_sizes, int n_in,
                              void* d_out, int out_size, void* d_ws, size_t ws_size,
                              hipStream_t stream)
{
  const float* x        = (const float*)d_in[0];
  const float* cls_lab  = (const float*)d_in[1];
  const float* conv1_w  = (const float*)d_in[2];
  const float* bn1_g    = (const float*)d_in[3];
  const float* bn1_b    = (const float*)d_in[4];
  const float* conv2_w  = (const float*)d_in[5];
  const float* bn2_g    = (const float*)d_in[6];
  const float* bn2_b    = (const float*)d_in[7];
  const float* sa_qk_w  = (const float*)d_in[8];
  const float* sa_v_w   = (const float*)d_in[9];
  const float* sa_v_b   = (const float*)d_in[10];
  const float* sa_t_w   = (const float*)d_in[11];
  const float* sa_t_b   = (const float*)d_in[12];
  const float* sa_bn_g  = (const float*)d_in[13];
  const float* sa_bn_b  = (const float*)d_in[14];
  const float* fuse_w   = (const float*)d_in[15];
  const float* fuse_g   = (const float*)d_in[16];
  const float* fuse_b   = (const float*)d_in[17];
  const float* label_w  = (const float*)d_in[18];
  const float* label_g  = (const float*)d_in[19];
  const float* label_b  = (const float*)d_in[20];
  const float* c1_w     = (const float*)d_in[21];
  const float* c1_b     = (const float*)d_in[22];
  const float* bns1_g   = (const float*)d_in[23];
  const float* bns1_b   = (const float*)d_in[24];
  const float* c2_w     = (const float*)d_in[25];
  const float* c2_b     = (const float*)d_in[26];
  const float* bns2_g   = (const float*)d_in[27];
  const float* bns2_b   = (const float*)d_in[28];
  const float* c3_w     = (const float*)d_in[29];
  const float* c3_b     = (const float*)d_in[30];
  float* outp = (float*)d_out;

  float* f = (float*)d_ws;
  size_t off = 0;
  auto us = [&](size_t n_ushort) { unsigned short* p = (unsigned short*)(f + off);
                                   off += (n_ushort + 1) / 2; return p; };
  unsigned short* h0h  = us((size_t)BB*NP*128);
  unsigned short* h0l  = us((size_t)BB*NP*128);
  unsigned short* h1h  = us((size_t)BB*NP*128);
  unsigned short* h1l  = us((size_t)BB*NP*128);
  unsigned short* hch  = us((size_t)BB*NP*512);
  unsigned short* hcl  = us((size_t)BB*NP*512);
  unsigned short* qTh  = us((size_t)BB*NP*32);
  unsigned short* qTl  = us((size_t)BB*NP*32);
  unsigned short* vb   = us((size_t)BB*128*NP);
  unsigned short* dhb  = us((size_t)BB*NP*128);
  unsigned short* dlb  = us((size_t)BB*NP*128);
  float* pmax  = f + off; off += (size_t)BB*8*NP;
  float* psum  = f + off; off += (size_t)BB*8*NP;
  float* rmaxb = f + off; off += (size_t)BB*NP;
  float* rinvb = f + off; off += (size_t)BB*NP;
  float* csp   = f + off; off += (size_t)BB*4*NP;
  float* pmx   = f + off; off += (size_t)BB*16*1024;
  float* psm   = f + off; off += (size_t)BB*16*1024;
  float* xm    = f + off; off += (size_t)BB*1024;
  float* xa    = f + off; off += (size_t)BB*1024;
  float* clsf  = f + off; off += (size_t)BB*64;
  float* gb    = f + off; off += (size_t)BB*512;
  off = (off + 255) & ~(size_t)255;
  float* ypart = f + off;                               // BB*4*NP*128 floats
  unsigned short* fuh = (unsigned short*)ypart;         // alias: fuse nT (after ypart dead)
  unsigned short* ful = fuh + (size_t)BB*NP*1024;
  unsigned short* o1h = ful + (size_t)BB*NP*1024;
  unsigned short* o1l = o1h + (size_t)BB*NP*512;
  unsigned short* o2h = o1l + (size_t)BB*NP*512;
  unsigned short* o2l = o2h + (size_t)BB*NP*256;

  const dim3 blk(256);

  k_conv1<<<dim3(128, BB), blk, 0, stream>>>(x, conv1_w, bn1_g, bn1_b, h0h, h0l);

  // conv2: 128<-128, bn+relu -> h1 nT
  k_mm<1,true,false,false><<<dim3(2,32,BB), blk, 0, stream>>>(
      h0h, h0l, 128, (size_t)NP*128, conv2_w, 128, nullptr, 0, bn2_g, bn2_b,
      nullptr, nullptr, 0, 0, h1h, h1l, 128, (size_t)NP*128, nullptr, 0, 128, 128);

  for (int i = 0; i < 4; ++i) {
    const unsigned short* hinh = (i == 0) ? h1h : hch + (size_t)(i-1)*128;
    const unsigned short* hinl = (i == 0) ? h1l : hcl + (size_t)(i-1)*128;
    const int ldH = (i == 0) ? 128 : 512;
    const size_t H_bs = (size_t)NP * ldH;

    // q: 32<-128 -> qT nT hi/lo
    k_mm<0,false,false,false><<<dim3(1,32,BB), blk, 0, stream>>>(
        hinh, hinl, ldH, H_bs, sa_qk_w + (size_t)i*32*128, 128, nullptr, 0,
        nullptr, nullptr, nullptr, nullptr, 0, 0,
        qTh, qTl, 32, (size_t)NP*32, nullptr, 0, 32, 128);

    // v: 128<-128 + v_b -> bf16 [C][N]
    k_mm<0,false,false,true><<<dim3(2,32,BB), blk, 0, stream>>>(
        hinh, hinl, ldH, H_bs, sa_v_w + (size_t)i*128*128, 128,
        sa_v_b + (size_t)i*128, 0, nullptr, nullptr,
        nullptr, nullptr, 0, 0, nullptr, nullptr, 0, 0,
        (float*)vb, (size_t)128*NP, 128, 128);

    k_passA<<<dim3(64,8,BB), blk, 0, stream>>>(qTh, qTl, pmax, psum);
    k_combineA<<<dim3(BB*NP/256), blk, 0, stream>>>(pmax, psum, rmaxb, rinvb);
    k_passB<<<dim3(64,4,BB), blk, 0, stream>>>(qTh, qTl, vb, rmaxb, rinvb, ypart, csp);
    k_combineB<<<dim3(BB*NP*128/256), blk, 0, stream>>>(
        ypart, csp, hinh, hinl, ldH, H_bs, dhb, dlb);

    // t: 128<-128 on (h - x_r), + t_b, bn, relu, + residual h -> hcat slice nT
    k_mm<1,true,true,false><<<dim3(2,32,BB), blk, 0, stream>>>(
        dhb, dlb, 128, (size_t)NP*128, sa_t_w + (size_t)i*128*128, 128,
        sa_t_b + (size_t)i*128, 0, sa_bn_g + (size_t)i*128, sa_bn_b + (size_t)i*128,
        hinh, hinl, ldH, H_bs,
        hch + (size_t)i*128, hcl + (size_t)i*128, 512, (size_t)NP*512,
        nullptr, 0, 128, 128);
  }

  // fuse: 1024<-512, bn + leaky -> fuse nT
  k_mm<2,true,false,false><<<dim3(16,32,BB), blk, 0, stream>>>(
      hch, hcl, 512, (size_t)NP*512, fuse_w, 512, nullptr, 0, fuse_g, fuse_b,
      nullptr, nullptr, 0, 0, fuh, ful, 1024, (size_t)NP*1024, nullptr, 0, 1024, 512);

  k_maxavg_p<<<dim3(16,16,BB), blk, 0, stream>>>(fuh, ful, pmx, psm);
  k_maxavg_c<<<dim3(BB*1024/256), blk, 0, stream>>>(pmx, psm, xm, xa);
  k_cls<<<dim3(1), dim3(128), 0, stream>>>(cls_lab, label_w, label_g, label_b, clsf);
  k_gbias<<<dim3(512, BB), blk, 0, stream>>>(c1_w, xm, xa, clsf, c1_b, gb);

  // convs1: 512<-1024 (+gb per b,o), bn, relu -> out1 nT
  k_mm<1,true,false,false><<<dim3(8,32,BB), blk, 0, stream>>>(
      fuh, ful, 1024, (size_t)NP*1024, c1_w, 3136, gb, 512, bns1_g, bns1_b,
      nullptr, nullptr, 0, 0, o1h, o1l, 512, (size_t)NP*512, nullptr, 0, 512, 1024);

  // convs2: 256<-512 + c2_b, bn, relu -> out2 nT
  k_mm<1,true,false,false><<<dim3(4,32,BB), blk, 0, stream>>>(
      o1h, o1l, 512, (size_t)NP*512, c2_w, 512, c2_b, 0, bns2_g, bns2_b,
      nullptr, nullptr, 0, 0, o2h, o2l, 256, (size_t)NP*256, nullptr, 0, 256, 512);

  // convs3: 50<-256 + c3_b -> fp32 [50][N] output
  k_mm<0,false,false,false><<<dim3(1,32,BB), blk, 0, stream>>>(
      o2h, o2l, 256, (size_t)NP*256, c3_w, 256, c3_b, 0, nullptr, nullptr,
      nullptr, nullptr, 0, 0, nullptr, nullptr, 0, 0,
      outp, (size_t)50*NP, 50, 256);
}